// Round 2
// baseline (2255.936 us; speedup 1.0000x reference)
//
#include <hip/hip_runtime.h>
#include <math.h>

#define PI_F 3.14159265358979323846f

// Problem sizes
#define C_SEQ   4096
#define C_B     8
#define C_D     512
#define C_FREQ  2049                  // SEQ/2+1
#define C_FPAD  2052                  // yf row stride (16B-aligned float4 rows)
#define C_NTOK  (C_B * C_FREQ)        // 16392
#define C_NSLOT (2 * C_NTOK)          // 32784
#define C_CHUNK 512                   // d_ff chunk (hid is bf16 now)
#define C_NCHUNK 4
#define C_E     8
#define C_TOKD  ((size_t)C_NTOK * 512)   // 8,392,704 floats
#define C_PB    ((size_t)C_FREQ * 1024)  // 2,098,176 floats (one batch F-slab)
#define C_CSTRIDE 16                  // counter padding: 16 ints = 64B cacheline

typedef __attribute__((ext_vector_type(8))) short bf8_t;   // 8 bf16 (4 VGPRs)
typedef __attribute__((ext_vector_type(4))) float f4_t;    // MFMA acc

__device__ __forceinline__ unsigned short f2bf(float f) {
    union { float f; unsigned u; } v; v.f = f;
    unsigned r = v.u + 0x7FFF + ((v.u >> 16) & 1);   // RNE
    return (unsigned short)(r >> 16);
}

// ---------------------------------------------------------------------------
// Transpose: in (Z, R, C) -> out (Z, C, R); grid (ceil(C/32), ceil(R/32), Z)
// ---------------------------------------------------------------------------
__global__ __launch_bounds__(256) void k_transpose(const float* __restrict__ in,
                                                   float* __restrict__ out,
                                                   int R, int C) {
    __shared__ float t[32][33];
    int c0 = blockIdx.x * 32, r0 = blockIdx.y * 32;
    const float* inb = in + (size_t)blockIdx.z * R * C;
    float* outb = out + (size_t)blockIdx.z * R * C;
    int tx = threadIdx.x, ty = threadIdx.y;
#pragma unroll
    for (int i = 0; i < 4; ++i) {
        int r = r0 + ty + i * 8, c = c0 + tx;
        if (r < R && c < C) t[ty + i * 8][tx] = inb[(size_t)r * C + c];
    }
    __syncthreads();
#pragma unroll
    for (int i = 0; i < 4; ++i) {
        int c = c0 + ty + i * 8, r = r0 + tx;
        if (r < R && c < C) outb[(size_t)c * R + r] = t[tx][ty + i * 8];
    }
}

// ---------------------------------------------------------------------------
// 4096-pt in-place radix-2 DIT FFT in LDS (32 KB). Bit-reversed input order.
// ---------------------------------------------------------------------------
__device__ __forceinline__ int brev12(int x) {
    return (int)(__brev((unsigned)x) >> 20);
}

__device__ __forceinline__ void fft4096_inplace(float* re, float* im, int tid) {
    for (int s = 1; s <= 12; ++s) {
        int half = 1 << (s - 1);
        float wstep = -2.f * PI_F / (float)(1 << s);
        __syncthreads();
#pragma unroll
        for (int u = 0; u < 8; ++u) {
            int bf = tid + u * 256;                 // 0..2047
            int j = bf & (half - 1);
            int i1 = ((bf >> (s - 1)) << s) + j;
            int i2 = i1 + half;
            float sn, cs;
            __sincosf(wstep * (float)j, &sn, &cs);
            float ur = re[i1], ui = im[i1];
            float vr = re[i2], vi = im[i2];
            float tr = vr * cs - vi * sn;
            float ti = vr * sn + vi * cs;
            re[i1] = ur + tr; im[i1] = ui + ti;
            re[i2] = ur - tr; im[i2] = ui - ti;
        }
    }
    __syncthreads();
}

// rfft(ortho): xt (B, D, S) -> yf (B, 1024, FPAD)  rows: c=d real, c=512+d imag
__global__ __launch_bounds__(256) void k_fft_fwd(const float* __restrict__ xt,
                                                 float* __restrict__ yf) {
    __shared__ float re[4096], im[4096];
    int tid = threadIdx.x;
    int sig = blockIdx.x;
    int b = sig >> 9, d = sig & 511;
    const float* src = xt + ((size_t)b * C_D + d) * C_SEQ;
    for (int i = tid; i < 4096; i += 256) {
        int r = brev12(i);
        re[r] = src[i];
        im[r] = 0.f;
    }
    fft4096_inplace(re, im, tid);
    float* outRe = yf + ((size_t)b * 1024 + d) * C_FPAD;
    float* outIm = yf + ((size_t)b * 1024 + 512 + d) * C_FPAD;
    const float scale = 1.f / 64.f;                // 1/sqrt(4096)
    for (int k = tid; k < C_FPAD; k += 256) {
        float vr = (k < C_FREQ) ? re[k] * scale : 0.f;
        float vi = (k < C_FREQ) ? im[k] * scale : 0.f;
        outRe[k] = vr;
        outIm[k] = vi;
    }
}

// irfft(ortho), ONE batch: ofT_b (1024, F) -> otT_b (D, S)
__global__ __launch_bounds__(256) void k_fft_inv(const float* __restrict__ ofTb,
                                                 float* __restrict__ otTb) {
    __shared__ float re[4096], im[4096];
    int tid = threadIdx.x;
    int d = blockIdx.x;                            // 0..511
    const float* inRe = ofTb + (size_t)d * C_FREQ;
    const float* inIm = ofTb + (size_t)(512 + d) * C_FREQ;
    for (int i = tid; i < 4096; i += 256) {
        float zr, zi;
        if (i <= 2048) { zr = inRe[i];        zi = -inIm[i]; }
        else           { zr = inRe[4096 - i]; zi =  inIm[4096 - i]; }
        int r = brev12(i);
        re[r] = zr;
        im[r] = zi;
    }
    fft4096_inplace(re, im, tid);
    float* dst = otTb + (size_t)d * C_SEQ;
    const float scale = 1.f / 64.f;
    for (int n = tid; n < 4096; n += 256) dst[n] = re[n] * scale;
}

// ---------------------------------------------------------------------------
// f32 SGEMM v2: 128x128 block, 256 threads, 8x8 acc/thread, BK=16.
// 64 FMAs per 4 ds_read_b128 -> VALU-bound (~2x the 4x4 version's ratio).
// ---------------------------------------------------------------------------
#define GEMM8_COMPUTE()                                                       \
    _Pragma("unroll")                                                         \
    for (int kk = 0; kk < 16; ++kk) {                                         \
        float4 a0 = *(const float4*)&As[kk][ty * 4];                          \
        float4 a1 = *(const float4*)&As[kk][64 + ty * 4];                     \
        float4 b0 = *(const float4*)&Bs[kk][tx * 4];                          \
        float4 b1 = *(const float4*)&Bs[kk][64 + tx * 4];                     \
        float ar[8] = {a0.x, a0.y, a0.z, a0.w, a1.x, a1.y, a1.z, a1.w};       \
        float br[8] = {b0.x, b0.y, b0.z, b0.w, b1.x, b1.y, b1.z, b1.w};       \
        _Pragma("unroll")                                                     \
        for (int i = 0; i < 8; ++i)                                           \
            _Pragma("unroll")                                                 \
            for (int j = 0; j < 8; ++j) acc[i][j] += ar[i] * br[j];           \
    }

// h = yf^T @ pin_w + pin_b. yf[b] (1024, FPAD) K-major; out h (NTOK,512).
// grid (17, 4, B)
__global__ __launch_bounds__(256) void k_gemm_pin(const float* __restrict__ yf,
                                                  const float* __restrict__ pw,
                                                  const float* __restrict__ pb,
                                                  float* __restrict__ h) {
    __shared__ float As[16][128];
    __shared__ float Bs[16][128];
    int b = blockIdx.z;
    int m0 = blockIdx.x * 128;   // f
    int n0 = blockIdx.y * 128;   // out feature
    int tid = threadIdx.x;
    int tx = tid & 15, ty = tid >> 4;
    int sr = tid >> 5;           // 0..7
    int sc = (tid & 31) * 4;     // 0..124
    const float* Ab = yf + (size_t)b * 1024 * C_FPAD;
    float acc[8][8] = {};
    for (int k0 = 0; k0 < 1024; k0 += 16) {
#pragma unroll
        for (int half = 0; half < 2; ++half) {
            int kk = sr + half * 8;
            float4 av = make_float4(0.f, 0.f, 0.f, 0.f);
            if (m0 + sc < C_FPAD)
                av = *(const float4*)&Ab[(size_t)(k0 + kk) * C_FPAD + m0 + sc];
            *(float4*)&As[kk][sc] = av;
            *(float4*)&Bs[kk][sc] = *(const float4*)&pw[(size_t)(k0 + kk) * 512 + n0 + sc];
        }
        __syncthreads();
        GEMM8_COMPUTE();
        __syncthreads();
    }
#pragma unroll
    for (int ih = 0; ih < 2; ++ih)
#pragma unroll
        for (int i = 0; i < 4; ++i) {
            int m = m0 + ih * 64 + ty * 4 + i;
            if (m < C_FREQ) {
                float* orow = h + ((size_t)b * C_FREQ + m) * 512;
#pragma unroll
                for (int jh = 0; jh < 2; ++jh) {
                    int n = n0 + jh * 64 + tx * 4;
                    float4 ov;
                    ov.x = acc[ih * 4 + i][jh * 4 + 0] + pb[n + 0];
                    ov.y = acc[ih * 4 + i][jh * 4 + 1] + pb[n + 1];
                    ov.z = acc[ih * 4 + i][jh * 4 + 2] + pb[n + 2];
                    ov.w = acc[ih * 4 + i][jh * 4 + 3] + pb[n + 3];
                    *(float4*)&orow[n] = ov;
                }
            }
        }
}

__global__ void k_zero(int* p, int n) {
    int i = blockIdx.x * 64 + threadIdx.x;
    if (i < n) p[i] = 0;
}

// ---------------------------------------------------------------------------
// Router v3: one wave handles 8 tokens; router weights held in registers.
// Counts aggregated in LDS; one padded global atomic per expert per block.
// ---------------------------------------------------------------------------
__global__ __launch_bounds__(256) void k_router(const float* __restrict__ h,
                                                const float* __restrict__ rw,
                                                const float* __restrict__ rb,
                                                int* __restrict__ topk_idx,
                                                float* __restrict__ topk_w,
                                                int* __restrict__ counts) {
    __shared__ int lc[C_E];
    if (threadIdx.x < C_E) lc[threadIdx.x] = 0;
    __syncthreads();
    int wave = threadIdx.x >> 6, lane = threadIdx.x & 63;
    // wreg[j][e] = rw[lane*8 + j][e]
    float wreg[8][8];
#pragma unroll
    for (int j = 0; j < 8; ++j) {
        const float4* rp = (const float4*)&rw[(size_t)(lane * 8 + j) * 8];
        float4 r0 = rp[0], r1 = rp[1];
        wreg[j][0] = r0.x; wreg[j][1] = r0.y; wreg[j][2] = r0.z; wreg[j][3] = r0.w;
        wreg[j][4] = r1.x; wreg[j][5] = r1.y; wreg[j][6] = r1.z; wreg[j][7] = r1.w;
    }
    int baseT = (blockIdx.x * 4 + wave) * 8;
    for (int tt = 0; tt < 8; ++tt) {
        int t = baseT + tt;
        bool valid = (t < C_NTOK);
        int tc = valid ? t : (C_NTOK - 1);
        const float4* hp = (const float4*)&h[(size_t)tc * 512 + lane * 8];
        float4 h0 = hp[0], h1 = hp[1];
        float hv[8] = {h0.x, h0.y, h0.z, h0.w, h1.x, h1.y, h1.z, h1.w};
        float part[8] = {};
#pragma unroll
        for (int j = 0; j < 8; ++j)
#pragma unroll
            for (int e = 0; e < 8; ++e) part[e] += hv[j] * wreg[j][e];
        // full-wave butterfly (all lanes active)
#pragma unroll
        for (int off = 1; off < 64; off <<= 1)
#pragma unroll
            for (int e = 0; e < 8; ++e) part[e] += __shfl_xor(part[e], off);
        if (valid && lane == 0) {
            float v[8];
#pragma unroll
            for (int e = 0; e < 8; ++e) v[e] = part[e] + rb[e];
            int i1 = 0;
            for (int q = 1; q < 8; ++q) if (v[q] > v[i1]) i1 = q;
            int i2 = -1;
            for (int q = 0; q < 8; ++q)
                if (q != i1 && (i2 < 0 || v[q] > v[i2])) i2 = q;
            float w1 = 1.f / (1.f + __expf(v[i2] - v[i1]));
            topk_idx[t * 2] = i1; topk_idx[t * 2 + 1] = i2;
            topk_w[t * 2] = w1;   topk_w[t * 2 + 1] = 1.f - w1;
            atomicAdd(&lc[i1], 1);    // LDS atomic — fast
            atomicAdd(&lc[i2], 1);
        }
    }
    __syncthreads();
    if (threadIdx.x < C_E) {
        int c = lc[threadIdx.x];
        if (c > 0) atomicAdd(&counts[threadIdx.x * C_CSTRIDE], c);
    }
}

__global__ void k_scan(const int* __restrict__ counts, int* __restrict__ offsets,
                       int* __restrict__ cursor) {
    if (threadIdx.x == 0) {
        int acc = 0;
        for (int e = 0; e < C_E; ++e) {
            offsets[e] = acc;
            cursor[e * C_CSTRIDE] = acc;
            acc += counts[e * C_CSTRIDE];
        }
        offsets[C_E] = acc;
    }
}

// ---------------------------------------------------------------------------
// Fill v2: block-level two-phase reservation (LDS histogram + rank, one
// padded global atomic per expert per block, conflict-free scatter).
// ---------------------------------------------------------------------------
__global__ __launch_bounds__(256) void k_fill(const int* __restrict__ topk_idx,
                                              const float* __restrict__ topk_w,
                                              int* __restrict__ cursor,
                                              int* __restrict__ tok_list,
                                              float* __restrict__ gate_list) {
    __shared__ int lc[C_E];
    __shared__ int lbase[C_E];
    int tid = threadIdx.x;
    if (tid < C_E) lc[tid] = 0;
    __syncthreads();
    int t = blockIdx.x * 256 + tid;
    int e0 = 0, e1 = 0, p0 = 0, p1 = 0;
    float w0 = 0.f, w1 = 0.f;
    bool valid = (t < C_NTOK);
    if (valid) {
        e0 = topk_idx[t * 2];     e1 = topk_idx[t * 2 + 1];
        w0 = topk_w[t * 2];       w1 = topk_w[t * 2 + 1];
        p0 = atomicAdd(&lc[e0], 1);
        p1 = atomicAdd(&lc[e1], 1);
    }
    __syncthreads();
    if (tid < C_E) {
        int c = lc[tid];
        lbase[tid] = (c > 0) ? atomicAdd(&cursor[tid * C_CSTRIDE], c) : 0;
    }
    __syncthreads();
    if (valid) {
        int pos0 = lbase[e0] + p0;
        tok_list[pos0] = t; gate_list[pos0] = w0;
        int pos1 = lbase[e1] + p1;
        tok_list[pos1] = t; gate_list[pos1] = w1;
    }
}

// ---------------------------------------------------------------------------
// Expert layer 1 (bf16 MFMA): hid_bf[slot] = gelu(h[tok] @ w1[e][:,ffc0:+512])
// Tile 64x64, BK=32, 4 waves (one 16-row strip each, 4 n-tiles).
// grid (257, 8, E)
// ---------------------------------------------------------------------------
__global__ __launch_bounds__(256) void k_expert1(const float* __restrict__ h,
                                                 const float* __restrict__ w1,
                                                 const float* __restrict__ b1,
                                                 const int* __restrict__ offsets,
                                                 const int* __restrict__ tok_list,
                                                 unsigned short* __restrict__ hid_bf,
                                                 int ffc0) {
    int e = blockIdx.z;
    int segStart = offsets[e], segEnd = offsets[e + 1];
    int segLen = segEnd - segStart;
    int m0 = blockIdx.x * 64;
    if (m0 >= segLen) return;
    int n0 = blockIdx.y * 64;                      // within chunk [0,512)
    __shared__ unsigned short As[64][40];          // [m][k] pad->80B rows
    __shared__ unsigned short Bs[64][40];          // [n][k]
    __shared__ int tok[64];
    int tid = threadIdx.x;
    if (tid < 64) {
        int mr = m0 + tid;
        tok[tid] = (mr < segLen) ? tok_list[segStart + mr] : -1;
    }
    __syncthreads();
    int wave = tid >> 6, lane = tid & 63;
    int fm = lane & 15, quad = lane >> 4;
    int ar = tid >> 2, ak = (tid & 3) * 8;         // A staging: row, k-off
    int bn = tid & 63, bk = (tid >> 6) * 8;        // B staging: n, k-off
    const float* w1e = w1 + (size_t)e * 512 * 2048 + ffc0;
    f4_t acc[4] = {{0,0,0,0},{0,0,0,0},{0,0,0,0},{0,0,0,0}};
    for (int k0 = 0; k0 < 512; k0 += 32) {
        // A: gather + convert
        float4 a0 = make_float4(0,0,0,0), a1 = make_float4(0,0,0,0);
        int trow = tok[ar];
        if (trow >= 0) {
            const float4* hp = (const float4*)&h[(size_t)trow * 512 + k0 + ak];
            a0 = hp[0]; a1 = hp[1];
        }
        uint4 pa;
        pa.x = f2bf(a0.x) | ((unsigned)f2bf(a0.y) << 16);
        pa.y = f2bf(a0.z) | ((unsigned)f2bf(a0.w) << 16);
        pa.z = f2bf(a1.x) | ((unsigned)f2bf(a1.y) << 16);
        pa.w = f2bf(a1.z) | ((unsigned)f2bf(a1.w) << 16);
        *(uint4*)&As[ar][ak] = pa;
        // B: strided-k coalesced-n reads + convert (transpose into [n][k])
        float bv[8];
#pragma unroll
        for (int j = 0; j < 8; ++j)
            bv[j] = w1e[(size_t)(k0 + bk + j) * 2048 + n0 + bn];
        uint4 pbk;
        pbk.x = f2bf(bv[0]) | ((unsigned)f2bf(bv[1]) << 16);
        pbk.y = f2bf(bv[2]) | ((unsigned)f2bf(bv[3]) << 16);
        pbk.z = f2bf(bv[4]) | ((unsigned)f2bf(bv[5]) << 16);
        pbk.w = f2bf(bv[6]) | ((unsigned)f2bf(bv[7]) << 16);
        *(uint4*)&Bs[bn][bk] = pbk;
        __syncthreads();
        bf8_t af = *(const bf8_t*)&As[wave * 16 + fm][quad * 8];
#pragma unroll
        for (int t = 0; t < 4; ++t) {
            bf8_t bf = *(const bf8_t*)&Bs[t * 16 + fm][quad * 8];
            acc[t] = __builtin_amdgcn_mfma_f32_16x16x32_bf16(af, bf, acc[t], 0, 0, 0);
        }
        __syncthreads();
    }
    // epilogue: C/D layout col=lane&15, row=quad*4+reg
#pragma unroll
    for (int t = 0; t < 4; ++t) {
#pragma unroll
        for (int r = 0; r < 4; ++r) {
            int ml = wave * 16 + quad * 4 + r;
            int mr = m0 + ml;
            if (mr < segLen) {
                int n = n0 + t * 16 + fm;
                float xv = acc[t][r] + b1[(size_t)e * 2048 + ffc0 + n];
                float gl = 0.5f * xv * (1.f + erff(xv * 0.70710678118654752f));
                hid_bf[(size_t)(segStart + mr) * C_CHUNK + n] = f2bf(gl);
            }
        }
    }
}

// ---------------------------------------------------------------------------
// Expert layer 2 (bf16 MFMA): moe[tok] += gate*(hid_bf @ w2[e][ffc0:+512,:])
// K=512(chunk), N=512. grid (257, 8, E)
// ---------------------------------------------------------------------------
__global__ __launch_bounds__(256) void k_expert2(const unsigned short* __restrict__ hid_bf,
                                                 const float* __restrict__ w2,
                                                 const float* __restrict__ b2,
                                                 const int* __restrict__ offsets,
                                                 const int* __restrict__ tok_list,
                                                 const float* __restrict__ gate_list,
                                                 float* __restrict__ moe,
                                                 int ffc0, int addBias) {
    int e = blockIdx.z;
    int segStart = offsets[e], segEnd = offsets[e + 1];
    int segLen = segEnd - segStart;
    int m0 = blockIdx.x * 64;
    if (m0 >= segLen) return;
    int n0 = blockIdx.y * 64;                      // within d_model [0,512)
    __shared__ unsigned short As[64][40];
    __shared__ unsigned short Bs[64][40];
    __shared__ int tokS[64];
    __shared__ float gateS[64];
    int tid = threadIdx.x;
    if (tid < 64) {
        int mr = m0 + tid;
        tokS[tid]  = (mr < segLen) ? tok_list[segStart + mr] : 0;
        gateS[tid] = (mr < segLen) ? gate_list[segStart + mr] : 0.f;
    }
    __syncthreads();
    int wave = tid >> 6, lane = tid & 63;
    int fm = lane & 15, quad = lane >> 4;
    int ar = tid >> 2, ak = (tid & 3) * 8;
    int bn = tid & 63, bk = (tid >> 6) * 8;
    const float* w2e = w2 + (size_t)e * 2048 * 512 + (size_t)ffc0 * 512;
    f4_t acc[4] = {{0,0,0,0},{0,0,0,0},{0,0,0,0},{0,0,0,0}};
    for (int k0 = 0; k0 < C_CHUNK; k0 += 32) {
        // A: hid_bf rows are contiguous slots (no gather), already bf16
        uint4 pa = make_uint4(0, 0, 0, 0);
        if (m0 + ar < segLen)
            pa = *(const uint4*)&hid_bf[(size_t)(segStart + m0 + ar) * C_CHUNK + k0 + ak];
        *(uint4*)&As[ar][ak] = pa;
        // B: w2 f32 -> bf16, transpose into [n][k]
        float bv[8];
#pragma unroll
        for (int j = 0; j < 8; ++j)
            bv[j] = w2e[(size_t)(k0 + bk + j) * 512 + n0 + bn];
        uint4 pbk;
        pbk.x = f2bf(bv[0]) | ((unsigned)f2bf(bv[1]) << 16);
        pbk.y = f2bf(bv[2]) | ((unsigned)f2bf(bv[3]) << 16);
        pbk.z = f2bf(bv[4]) | ((unsigned)f2bf(bv[5]) << 16);
        pbk.w = f2bf(bv[6]) | ((unsigned)f2bf(bv[7]) << 16);
        *(uint4*)&Bs[bn][bk] = pbk;
        __syncthreads();
        bf8_t af = *(const bf8_t*)&As[wave * 16 + fm][quad * 8];
#pragma unroll
        for (int t = 0; t < 4; ++t) {
            bf8_t bf = *(const bf8_t*)&Bs[t * 16 + fm][quad * 8];
            acc[t] = __builtin_amdgcn_mfma_f32_16x16x32_bf16(af, bf, acc[t], 0, 0, 0);
        }
        __syncthreads();
    }
#pragma unroll
    for (int t = 0; t < 4; ++t) {
#pragma unroll
        for (int r = 0; r < 4; ++r) {
            int ml = wave * 16 + quad * 4 + r;
            int mr = m0 + ml;
            if (mr < segLen) {
                int n = n0 + t * 16 + fm;
                float v = acc[t][r];
                if (addBias) v += b2[(size_t)e * 512 + n];
                atomicAdd(&moe[(size_t)tokS[ml] * 512 + n], gateS[ml] * v);
            }
        }
    }
}

// ---------------------------------------------------------------------------
// of_b = moe_b @ pout_w + pout_b ; (F,512)x(512,1024). grid (17, 8), 128x128
// ---------------------------------------------------------------------------
__global__ __launch_bounds__(256) void k_gemm_pout(const float* __restrict__ moeb,
                                                   const float* __restrict__ pw,
                                                   const float* __restrict__ pb,
                                                   float* __restrict__ ofb) {
    __shared__ float As[16][128];
    __shared__ float Bs[16][128];
    int m0 = blockIdx.x * 128;
    int n0 = blockIdx.y * 128;
    int tid = threadIdx.x;
    int tx = tid & 15, ty = tid >> 4;
    int sr = tid >> 5, sc = (tid & 31) * 4;        // B staging
    int amr = tid >> 1;                            // A row 0..127
    int akc = (tid & 1) * 8;                       // A k-offset 0 or 8
    float acc[8][8] = {};
    for (int k0 = 0; k0 < 512; k0 += 16) {
        // A: 128 rows x 16 k, transpose into As[k][m]
        float4 av0 = make_float4(0.f, 0.f, 0.f, 0.f), av1 = av0;
        if (m0 + amr < C_FREQ) {
            const float4* ap = (const float4*)&moeb[(size_t)(m0 + amr) * 512 + k0 + akc];
            av0 = ap[0]; av1 = ap[1];
        }
        As[akc + 0][amr] = av0.x; As[akc + 1][amr] = av0.y;
        As[akc + 2][amr] = av0.z; As[akc + 3][amr] = av0.w;
        As[akc + 4][amr] = av1.x; As[akc + 5][amr] = av1.y;
        As[akc + 6][amr] = av1.z; As[akc + 7][amr] = av1.w;
#pragma unroll
        for (int half = 0; half < 2; ++half) {
            int kk = sr + half * 8;
            *(float4*)&Bs[kk][sc] = *(const float4*)&pw[(size_t)(k0 + kk) * 1024 + n0 + sc];
        }
        __syncthreads();
        GEMM8_COMPUTE();
        __syncthreads();
    }
#pragma unroll
    for (int ih = 0; ih < 2; ++ih)
#pragma unroll
        for (int i = 0; i < 4; ++i) {
            int m = m0 + ih * 64 + ty * 4 + i;
            if (m < C_FREQ) {
                float* orow = ofb + (size_t)m * 1024;
#pragma unroll
                for (int jh = 0; jh < 2; ++jh) {
                    int n = n0 + jh * 64 + tx * 4;
                    float4 ov;
                    ov.x = acc[ih * 4 + i][jh * 4 + 0] + pb[n + 0];
                    ov.y = acc[ih * 4 + i][jh * 4 + 1] + pb[n + 1];
                    ov.z = acc[ih * 4 + i][jh * 4 + 2] + pb[n + 2];
                    ov.w = acc[ih * 4 + i][jh * 4 + 3] + pb[n + 3];
                    *(float4*)&orow[n] = ov;
                }
            }
        }
}

// ---------------------------------------------------------------------------
// LayerNorm(d=512) + affine + residual.
// ---------------------------------------------------------------------------
__device__ __forceinline__ float block_sum512(float v, float* red, int tid) {
#pragma unroll
    for (int off = 32; off > 0; off >>= 1) v += __shfl_xor(v, off);
    __syncthreads();
    if ((tid & 63) == 0) red[tid >> 6] = v;
    __syncthreads();
    return red[0] + red[1] + red[2] + red[3];
}

__global__ __launch_bounds__(256) void k_ln(const float* __restrict__ ot,
                                            const float* __restrict__ x,
                                            const float* __restrict__ g,
                                            const float* __restrict__ bb,
                                            float* __restrict__ out) {
    __shared__ float red[4];
    int t = blockIdx.x;
    int tid = threadIdx.x;
    const float* row = ot + (size_t)t * 512;
    float v0 = row[tid], v1 = row[tid + 256];
    float total = block_sum512(v0 + v1, red, tid);
    float mu = total * (1.f / 512.f);
    float q0 = v0 - mu, q1 = v1 - mu;
    float var = block_sum512(q0 * q0 + q1 * q1, red, tid) * (1.f / 512.f);
    float rstd = rsqrtf(var + 1e-5f);
    const float* xr = x + (size_t)t * 512;
    float* orow = out + (size_t)t * 512;
    orow[tid]       = q0 * rstd * g[tid]       + bb[tid]       + xr[tid];
    orow[tid + 256] = q1 * rstd * g[tid + 256] + bb[tid + 256] + xr[tid + 256];
}

// ---------------------------------------------------------------------------
// ws (floats): Y=[0:2*TOKD) = yf (padded, spills ~25K floats into T1 head,
// dead at that time) -> (moe f32 | hid bf16) -> ot.
// T1=[2TOKD:2TOKD+PB) of_b; T2=[+PB] ofT_b.
// d_out: phase1 xt; phase2 h + routing lists; phase5 otT; LN overwrites.
// ---------------------------------------------------------------------------
extern "C" void kernel_launch(void* const* d_in, const int* in_sizes, int n_in,
                              void* d_out, int out_size, void* d_ws, size_t ws_size,
                              hipStream_t stream) {
    const float* x        = (const float*)d_in[0];
    const float* pin_w    = (const float*)d_in[1];
    const float* pin_b    = (const float*)d_in[2];
    const float* router_w = (const float*)d_in[3];
    const float* router_b = (const float*)d_in[4];
    const float* w1       = (const float*)d_in[5];
    const float* b1       = (const float*)d_in[6];
    const float* w2       = (const float*)d_in[7];
    const float* b2       = (const float*)d_in[8];
    const float* pout_w   = (const float*)d_in[9];
    const float* pout_b   = (const float*)d_in[10];
    const float* ln_g     = (const float*)d_in[11];
    const float* ln_b     = (const float*)d_in[12];
    float* outf = (float*)d_out;

    float* Y   = (float*)d_ws;                    // yf; later moe|hid; later ot
    float* moe = Y;                               // (NTOK,512) f32
    unsigned short* hid_bf = (unsigned short*)(Y + C_TOKD);  // (NSLOT,512) bf16
    float* T1  = Y + 2 * C_TOKD;                  // of_b (F,1024)
    float* T2  = T1 + C_PB;                       // ofT_b (1024,F)
    float* ot  = Y;                               // (B,S,D) final pre-LN

    float* xt    = outf;                          // (B,D,S)
    float* h     = outf;                          // (NTOK,512)
    float* topkw = outf + C_TOKD;
    float* gate  = topkw + C_NSLOT;
    int* topki   = (int*)(gate + C_NSLOT);
    int* tokl    = topki + C_NSLOT;
    int* counts  = tokl + C_NSLOT;                       // padded: 8*16 ints
    int* cursor  = counts + C_E * C_CSTRIDE;             // padded: 8*16 ints
    int* offsets = cursor + C_E * C_CSTRIDE;             // 9 ints
    float* otT   = outf;                          // (B,D,S)

    dim3 tb(32, 8);
    // 1. x (B,S,D) -> xt (B,D,S)
    k_transpose<<<dim3(C_D / 32, C_SEQ / 32, C_B), tb, 0, stream>>>(x, xt, C_SEQ, C_D);
    // 2. rfft (padded yf rows)
    k_fft_fwd<<<C_B * C_D, 256, 0, stream>>>(xt, Y);
    // 3. pin projection (128x128 tiles)
    k_gemm_pin<<<dim3(17, 4, C_B), 256, 0, stream>>>(Y, pin_w, pin_b, h);
    // init moe + counters (counts+cursor padded: 2*8*16 ints)
    hipMemsetAsync(moe, 0, C_TOKD * sizeof(float), stream);
    k_zero<<<4, 64, 0, stream>>>(counts, 2 * C_E * C_CSTRIDE);
    // 4. routing
    k_router<<<(C_NTOK + 31) / 32, 256, 0, stream>>>(h, router_w, router_b, topki, topkw, counts);
    k_scan<<<1, 64, 0, stream>>>(counts, offsets, cursor);
    k_fill<<<(C_NTOK + 255) / 256, 256, 0, stream>>>(topki, topkw, cursor, tokl, gate);
    // 5. grouped expert MLP, bf16 MFMA (d_ff chunked by 512)
    for (int c = 0; c < C_NCHUNK; ++c) {
        int ffc0 = c * C_CHUNK;
        k_expert1<<<dim3(257, 8, C_E), 256, 0, stream>>>(
            h, w1, b1, offsets, tokl, hid_bf, ffc0);
        k_expert2<<<dim3(257, 8, C_E), 256, 0, stream>>>(
            hid_bf, w2, b2, offsets, tokl, gate, moe, ffc0, c == 0 ? 1 : 0);
    }
    // 6. per batch: pout -> of_b, transpose, irfft -> otT
    for (int b = 0; b < C_B; ++b) {
        const float* moeb = moe + (size_t)b * C_FREQ * 512;
        k_gemm_pout<<<dim3(17, 8), 256, 0, stream>>>(moeb, pout_w, pout_b, T1);
        k_transpose<<<dim3(1024 / 32, (C_FREQ + 31) / 32, 1), tb, 0, stream>>>(
            T1, T2, C_FREQ, 1024);
        k_fft_inv<<<C_D, 256, 0, stream>>>(T2, otT + (size_t)b * C_D * C_SEQ);
    }
    // 7. otT -> ot (B,S,D) in ws
    k_transpose<<<dim3(C_SEQ / 32, C_D / 32, C_B), tb, 0, stream>>>(otT, ot, C_D, C_SEQ);
    // 8. LN + residual
    k_ln<<<C_B * C_SEQ, 256, 0, stream>>>(ot, x, ln_g, ln_b, outf);
}

// Round 6
// 1773.021 us; speedup vs baseline: 1.2724x; 1.2724x over previous
//
#include <hip/hip_runtime.h>
#include <math.h>

#define PI_F 3.14159265358979323846f

// Problem sizes
#define C_SEQ   4096
#define C_B     8
#define C_D     512
#define C_FREQ  2049                  // SEQ/2+1
#define C_FPAD  2052                  // yf row stride (padded)
#define C_NTOK  (C_B * C_FREQ)        // 16392
#define C_NSLOT (2 * C_NTOK)          // 32784
#define C_CHUNK 512                   // d_ff chunk (hid is bf16)
#define C_NCHUNK 4
#define C_E     8
#define C_TOKD  ((size_t)C_NTOK * 512)   // 8,392,704 floats
#define C_PB    ((size_t)C_FREQ * 1024)  // 2,098,176 floats (one batch F-slab)
#define C_CSTRIDE 16                  // counter padding: 16 ints = 64B cacheline

typedef __attribute__((ext_vector_type(8))) short bf8_t;   // 8 bf16 (4 VGPRs)
typedef __attribute__((ext_vector_type(4))) float f4_t;    // MFMA acc

__device__ __forceinline__ unsigned short f2bf(float f) {
    union { float f; unsigned u; } v; v.f = f;
    unsigned r = v.u + 0x7FFF + ((v.u >> 16) & 1);   // RNE
    return (unsigned short)(r >> 16);
}

// ---------------------------------------------------------------------------
// Transpose: in (Z, R, C) -> out (Z, C, R); grid (ceil(C/32), ceil(R/32), Z)
// ---------------------------------------------------------------------------
__global__ __launch_bounds__(256) void k_transpose(const float* __restrict__ in,
                                                   float* __restrict__ out,
                                                   int R, int C) {
    __shared__ float t[32][33];
    int c0 = blockIdx.x * 32, r0 = blockIdx.y * 32;
    const float* inb = in + (size_t)blockIdx.z * R * C;
    float* outb = out + (size_t)blockIdx.z * R * C;
    int tx = threadIdx.x, ty = threadIdx.y;
#pragma unroll
    for (int i = 0; i < 4; ++i) {
        int r = r0 + ty + i * 8, c = c0 + tx;
        if (r < R && c < C) t[ty + i * 8][tx] = inb[(size_t)r * C + c];
    }
    __syncthreads();
#pragma unroll
    for (int i = 0; i < 4; ++i) {
        int c = c0 + ty + i * 8, r = r0 + tx;
        if (r < R && c < C) outb[(size_t)c * R + r] = t[tx][ty + i * 8];
    }
}

// ---------------------------------------------------------------------------
// 4096-pt in-place radix-2 DIT FFT in LDS (32 KB). Bit-reversed input order.
// ---------------------------------------------------------------------------
__device__ __forceinline__ int brev12(int x) {
    return (int)(__brev((unsigned)x) >> 20);
}

__device__ __forceinline__ void fft4096_inplace(float* re, float* im, int tid) {
    for (int s = 1; s <= 12; ++s) {
        int half = 1 << (s - 1);
        float wstep = -2.f * PI_F / (float)(1 << s);
        __syncthreads();
#pragma unroll
        for (int u = 0; u < 8; ++u) {
            int bf = tid + u * 256;                 // 0..2047
            int j = bf & (half - 1);
            int i1 = ((bf >> (s - 1)) << s) + j;
            int i2 = i1 + half;
            float sn, cs;
            __sincosf(wstep * (float)j, &sn, &cs);
            float ur = re[i1], ui = im[i1];
            float vr = re[i2], vi = im[i2];
            float tr = vr * cs - vi * sn;
            float ti = vr * sn + vi * cs;
            re[i1] = ur + tr; im[i1] = ui + ti;
            re[i2] = ur - tr; im[i2] = ui - ti;
        }
    }
    __syncthreads();
}

// rfft(ortho): xt (B, D, S) -> yf (B, 1024, FPAD)  rows: c=d real, c=512+d imag
__global__ __launch_bounds__(256) void k_fft_fwd(const float* __restrict__ xt,
                                                 float* __restrict__ yf) {
    __shared__ float re[4096], im[4096];
    int tid = threadIdx.x;
    int sig = blockIdx.x;
    int b = sig >> 9, d = sig & 511;
    const float* src = xt + ((size_t)b * C_D + d) * C_SEQ;
    for (int i = tid; i < 4096; i += 256) {
        int r = brev12(i);
        re[r] = src[i];
        im[r] = 0.f;
    }
    fft4096_inplace(re, im, tid);
    float* outRe = yf + ((size_t)b * 1024 + d) * C_FPAD;
    float* outIm = yf + ((size_t)b * 1024 + 512 + d) * C_FPAD;
    const float scale = 1.f / 64.f;                // 1/sqrt(4096)
    for (int k = tid; k < C_FPAD; k += 256) {
        float vr = (k < C_FREQ) ? re[k] * scale : 0.f;
        float vi = (k < C_FREQ) ? im[k] * scale : 0.f;
        outRe[k] = vr;
        outIm[k] = vi;
    }
}

// irfft(ortho), ONE batch: ofT_b (1024, F) -> otT_b (D, S)
__global__ __launch_bounds__(256) void k_fft_inv(const float* __restrict__ ofTb,
                                                 float* __restrict__ otTb) {
    __shared__ float re[4096], im[4096];
    int tid = threadIdx.x;
    int d = blockIdx.x;                            // 0..511
    const float* inRe = ofTb + (size_t)d * C_FREQ;
    const float* inIm = ofTb + (size_t)(512 + d) * C_FREQ;
    for (int i = tid; i < 4096; i += 256) {
        float zr, zi;
        if (i <= 2048) { zr = inRe[i];        zi = -inIm[i]; }
        else           { zr = inRe[4096 - i]; zi =  inIm[4096 - i]; }
        int r = brev12(i);
        re[r] = zr;
        im[r] = zi;
    }
    fft4096_inplace(re, im, tid);
    float* dst = otTb + (size_t)d * C_SEQ;
    const float scale = 1.f / 64.f;
    for (int n = tid; n < 4096; n += 256) dst[n] = re[n] * scale;
}

// ---------------------------------------------------------------------------
// pin GEMM, bf16 MFMA: h[b,f,:] = yf[b]^T @ pin_w + pin_b.
// h feeds ONLY the experts (which round to bf16 anyway); routing no longer
// reads h (it uses the fused f32 path below). 64x64 tile, BK=32, 4 waves.
// grid (33, 8, B)
// ---------------------------------------------------------------------------
__global__ __launch_bounds__(256) void k_pin_mfma(const float* __restrict__ yf,
                                                  const float* __restrict__ pw,
                                                  const float* __restrict__ pb,
                                                  float* __restrict__ h) {
    int b = blockIdx.z;
    int m0 = blockIdx.x * 64;                      // f
    int n0 = blockIdx.y * 64;                      // out feature
    __shared__ unsigned short As[64][40];          // [m][k]
    __shared__ unsigned short Bs[64][40];          // [n][k]
    int tid = threadIdx.x;
    int wave = tid >> 6, lane = tid & 63;
    int fm = lane & 15, quad = lane >> 4;
    int sn = tid & 63, sk = (tid >> 6) * 8;        // staging: row, k-offset
    const float* Ab = yf + (size_t)b * 1024 * C_FPAD;
    bool mvalid = (m0 + sn) < C_FREQ;
    f4_t acc[4] = {{0,0,0,0},{0,0,0,0},{0,0,0,0},{0,0,0,0}};
    for (int k0 = 0; k0 < 1024; k0 += 32) {
        // A: strided-k coalesced-m reads (k-major source), pack -> [m][k]
        float av[8];
#pragma unroll
        for (int j = 0; j < 8; ++j)
            av[j] = mvalid ? Ab[(size_t)(k0 + sk + j) * C_FPAD + m0 + sn] : 0.f;
        uint4 pa;
        pa.x = f2bf(av[0]) | ((unsigned)f2bf(av[1]) << 16);
        pa.y = f2bf(av[2]) | ((unsigned)f2bf(av[3]) << 16);
        pa.z = f2bf(av[4]) | ((unsigned)f2bf(av[5]) << 16);
        pa.w = f2bf(av[6]) | ((unsigned)f2bf(av[7]) << 16);
        *(uint4*)&As[sn][sk] = pa;
        // B: same pattern, stride 512
        float bv[8];
#pragma unroll
        for (int j = 0; j < 8; ++j)
            bv[j] = pw[(size_t)(k0 + sk + j) * 512 + n0 + sn];
        uint4 pbk;
        pbk.x = f2bf(bv[0]) | ((unsigned)f2bf(bv[1]) << 16);
        pbk.y = f2bf(bv[2]) | ((unsigned)f2bf(bv[3]) << 16);
        pbk.z = f2bf(bv[4]) | ((unsigned)f2bf(bv[5]) << 16);
        pbk.w = f2bf(bv[6]) | ((unsigned)f2bf(bv[7]) << 16);
        *(uint4*)&Bs[sn][sk] = pbk;
        __syncthreads();
        bf8_t af = *(const bf8_t*)&As[wave * 16 + fm][quad * 8];
#pragma unroll
        for (int t = 0; t < 4; ++t) {
            bf8_t bf = *(const bf8_t*)&Bs[t * 16 + fm][quad * 8];
            acc[t] = __builtin_amdgcn_mfma_f32_16x16x32_bf16(af, bf, acc[t], 0, 0, 0);
        }
        __syncthreads();
    }
    // epilogue: C/D layout col=lane&15, row=quad*4+reg
#pragma unroll
    for (int t = 0; t < 4; ++t) {
#pragma unroll
        for (int r = 0; r < 4; ++r) {
            int m = m0 + wave * 16 + quad * 4 + r;
            if (m < C_FREQ) {
                int n = n0 + t * 16 + fm;
                h[((size_t)b * C_FREQ + m) * 512 + n] = acc[t][r] + pb[n];
            }
        }
    }
}

// ---------------------------------------------------------------------------
// pout GEMM, bf16 MFMA: of_b = moe_b @ pout_w + pout_b ; (F,512)x(512,1024).
// moe row-major, pout_w K-major. 64x64 tile, BK=32. grid (33, 16)
// ---------------------------------------------------------------------------
__global__ __launch_bounds__(256) void k_pout_mfma(const float* __restrict__ moeb,
                                                   const float* __restrict__ pw,
                                                   const float* __restrict__ pb,
                                                   float* __restrict__ ofb) {
    int m0 = blockIdx.x * 64;                      // f
    int n0 = blockIdx.y * 64;                      // out col of 1024
    __shared__ unsigned short As[64][40];
    __shared__ unsigned short Bs[64][40];
    int tid = threadIdx.x;
    int wave = tid >> 6, lane = tid & 63;
    int fm = lane & 15, quad = lane >> 4;
    int ar = tid >> 2, ak = (tid & 3) * 8;         // A: row, k-off
    int bn = tid & 63, bk = (tid >> 6) * 8;        // B: n, k-off
    bool avalid = (m0 + ar) < C_FREQ;
    f4_t acc[4] = {{0,0,0,0},{0,0,0,0},{0,0,0,0},{0,0,0,0}};
    for (int k0 = 0; k0 < 512; k0 += 32) {
        // A: row-major f32 -> bf16 [m][k]
        float4 a0 = make_float4(0,0,0,0), a1 = make_float4(0,0,0,0);
        if (avalid) {
            const float4* ap = (const float4*)&moeb[(size_t)(m0 + ar) * 512 + k0 + ak];
            a0 = ap[0]; a1 = ap[1];
        }
        uint4 pa;
        pa.x = f2bf(a0.x) | ((unsigned)f2bf(a0.y) << 16);
        pa.y = f2bf(a0.z) | ((unsigned)f2bf(a0.w) << 16);
        pa.z = f2bf(a1.x) | ((unsigned)f2bf(a1.y) << 16);
        pa.w = f2bf(a1.z) | ((unsigned)f2bf(a1.w) << 16);
        *(uint4*)&As[ar][ak] = pa;
        // B: strided-k coalesced-n (stride 1024), pack -> [n][k]
        float bv[8];
#pragma unroll
        for (int j = 0; j < 8; ++j)
            bv[j] = pw[(size_t)(k0 + bk + j) * 1024 + n0 + bn];
        uint4 pbk;
        pbk.x = f2bf(bv[0]) | ((unsigned)f2bf(bv[1]) << 16);
        pbk.y = f2bf(bv[2]) | ((unsigned)f2bf(bv[3]) << 16);
        pbk.z = f2bf(bv[4]) | ((unsigned)f2bf(bv[5]) << 16);
        pbk.w = f2bf(bv[6]) | ((unsigned)f2bf(bv[7]) << 16);
        *(uint4*)&Bs[bn][bk] = pbk;
        __syncthreads();
        bf8_t af = *(const bf8_t*)&As[wave * 16 + fm][quad * 8];
#pragma unroll
        for (int t = 0; t < 4; ++t) {
            bf8_t bf = *(const bf8_t*)&Bs[t * 16 + fm][quad * 8];
            acc[t] = __builtin_amdgcn_mfma_f32_16x16x32_bf16(af, bf, acc[t], 0, 0, 0);
        }
        __syncthreads();
    }
#pragma unroll
    for (int t = 0; t < 4; ++t) {
#pragma unroll
        for (int r = 0; r < 4; ++r) {
            int m = m0 + wave * 16 + quad * 4 + r;
            if (m < C_FREQ) {
                int n = n0 + t * 16 + fm;
                ofb[(size_t)m * 1024 + n] = acc[t][r] + pb[n];
            }
        }
    }
}

__global__ void k_zero(int* p, int n) {
    int i = blockIdx.x * 64 + threadIdx.x;
    if (i < n) p[i] = 0;
}

// grid-stride f32 zero (replaces mid-stream hipMemsetAsync — graph-capture
// tripwire elimination; same ~8 us cost at 2048 blocks)
__global__ __launch_bounds__(256) void k_zerof(float* __restrict__ p, unsigned long long n) {
    unsigned long long i = (unsigned long long)blockIdx.x * 256 + threadIdx.x;
    unsigned long long stride = (unsigned long long)gridDim.x * 256;
    for (; i < n; i += stride) p[i] = 0.f;
}

// ---------------------------------------------------------------------------
// Fused router weights (f32, exact): Wr = pin_w @ router_w  (1024 x 8),
// br = pin_b @ router_w + router_b. grid (32) x 256: thread=(k,e).
// ---------------------------------------------------------------------------
__global__ __launch_bounds__(256) void k_wr(const float* __restrict__ pin_w,
                                            const float* __restrict__ pin_b,
                                            const float* __restrict__ rw,
                                            const float* __restrict__ rb,
                                            float* __restrict__ wr,
                                            float* __restrict__ brv) {
    int k = blockIdx.x * 32 + (threadIdx.x >> 3);
    int e = threadIdx.x & 7;
    const float* pr = &pin_w[(size_t)k * 512];
    float s = 0.f;
    for (int d = 0; d < 512; ++d) s += pr[d] * rw[d * 8 + e];
    wr[k * 8 + e] = s;
    if (blockIdx.x == 0 && threadIdx.x < 8) {
        float s2 = 0.f;
        for (int d = 0; d < 512; ++d) s2 += pin_b[d] * rw[d * 8 + e];
        brv[e] = s2 + rb[e];
    }
}

// ---------------------------------------------------------------------------
// Router v4: logits computed DIRECTLY from yf in f32 (exact routing —
// decoupled from the bf16 h). One thread per token; lane-local top-k.
// yf columns are coalesced across threads (f contiguous). grid (9, B).
// ---------------------------------------------------------------------------
__global__ __launch_bounds__(256) void k_router2(const float* __restrict__ yf,
                                                 const float* __restrict__ wr,
                                                 const float* __restrict__ brv,
                                                 int* __restrict__ topk_idx,
                                                 float* __restrict__ topk_w,
                                                 int* __restrict__ counts) {
    __shared__ int lc[C_E];
    int tid = threadIdx.x;
    if (tid < C_E) lc[tid] = 0;
    __syncthreads();
    int b = blockIdx.y;
    int f = blockIdx.x * 256 + tid;
    bool valid = (f < C_FREQ);
    int fc = valid ? f : (C_FREQ - 1);
    const float* Ab = yf + (size_t)b * 1024 * C_FPAD + fc;
    float lg[8] = {};
#pragma unroll 4
    for (int k = 0; k < 1024; ++k) {
        float a = Ab[(size_t)k * C_FPAD];          // coalesced across lanes
        const float* w = &wr[k * 8];               // wave-uniform -> s_load
#pragma unroll
        for (int e = 0; e < 8; ++e) lg[e] += a * w[e];
    }
    if (valid) {
        float v[8];
#pragma unroll
        for (int e = 0; e < 8; ++e) v[e] = lg[e] + brv[e];
        int i1 = 0;
        for (int q = 1; q < 8; ++q) if (v[q] > v[i1]) i1 = q;
        int i2 = -1;
        for (int q = 0; q < 8; ++q)
            if (q != i1 && (i2 < 0 || v[q] > v[i2])) i2 = q;
        float w1 = 1.f / (1.f + __expf(v[i2] - v[i1]));
        int t = b * C_FREQ + f;
        topk_idx[t * 2] = i1; topk_idx[t * 2 + 1] = i2;
        topk_w[t * 2] = w1;   topk_w[t * 2 + 1] = 1.f - w1;
        atomicAdd(&lc[i1], 1);
        atomicAdd(&lc[i2], 1);
    }
    __syncthreads();
    if (tid < C_E) {
        int c = lc[tid];
        if (c > 0) atomicAdd(&counts[tid * C_CSTRIDE], c);
    }
}

__global__ void k_scan(const int* __restrict__ counts, int* __restrict__ offsets,
                       int* __restrict__ cursor) {
    if (threadIdx.x == 0) {
        int acc = 0;
        for (int e = 0; e < C_E; ++e) {
            offsets[e] = acc;
            cursor[e * C_CSTRIDE] = acc;
            acc += counts[e * C_CSTRIDE];
        }
        offsets[C_E] = acc;
    }
}

// ---------------------------------------------------------------------------
// Fill v2: block-level two-phase reservation (LDS histogram + rank, one
// padded global atomic per expert per block, conflict-free scatter).
// ---------------------------------------------------------------------------
__global__ __launch_bounds__(256) void k_fill(const int* __restrict__ topk_idx,
                                              const float* __restrict__ topk_w,
                                              int* __restrict__ cursor,
                                              int* __restrict__ tok_list,
                                              float* __restrict__ gate_list) {
    __shared__ int lc[C_E];
    __shared__ int lbase[C_E];
    int tid = threadIdx.x;
    if (tid < C_E) lc[tid] = 0;
    __syncthreads();
    int t = blockIdx.x * 256 + tid;
    int e0 = 0, e1 = 0, p0 = 0, p1 = 0;
    float w0 = 0.f, w1 = 0.f;
    bool valid = (t < C_NTOK);
    if (valid) {
        e0 = topk_idx[t * 2];     e1 = topk_idx[t * 2 + 1];
        w0 = topk_w[t * 2];       w1 = topk_w[t * 2 + 1];
        p0 = atomicAdd(&lc[e0], 1);
        p1 = atomicAdd(&lc[e1], 1);
    }
    __syncthreads();
    if (tid < C_E) {
        int c = lc[tid];
        lbase[tid] = (c > 0) ? atomicAdd(&cursor[tid * C_CSTRIDE], c) : 0;
    }
    __syncthreads();
    if (valid) {
        int pos0 = lbase[e0] + p0;
        tok_list[pos0] = t; gate_list[pos0] = w0;
        int pos1 = lbase[e1] + p1;
        tok_list[pos1] = t; gate_list[pos1] = w1;
    }
}

// ---------------------------------------------------------------------------
// Expert layer 1 (bf16 MFMA): hid_bf[slot] = gelu(h[tok] @ w1[e][:,ffc0:+512])
// Tile 64x64, BK=32, 4 waves (one 16-row strip each, 4 n-tiles).
// grid (257, 8, E)
// ---------------------------------------------------------------------------
__global__ __launch_bounds__(256) void k_expert1(const float* __restrict__ h,
                                                 const float* __restrict__ w1,
                                                 const float* __restrict__ b1,
                                                 const int* __restrict__ offsets,
                                                 const int* __restrict__ tok_list,
                                                 unsigned short* __restrict__ hid_bf,
                                                 int ffc0) {
    int e = blockIdx.z;
    int segStart = offsets[e], segEnd = offsets[e + 1];
    int segLen = segEnd - segStart;
    int m0 = blockIdx.x * 64;
    if (m0 >= segLen) return;
    int n0 = blockIdx.y * 64;                      // within chunk [0,512)
    __shared__ unsigned short As[64][40];          // [m][k] pad->80B rows
    __shared__ unsigned short Bs[64][40];          // [n][k]
    __shared__ int tok[64];
    int tid = threadIdx.x;
    if (tid < 64) {
        int mr = m0 + tid;
        tok[tid] = (mr < segLen) ? tok_list[segStart + mr] : -1;
    }
    __syncthreads();
    int wave = tid >> 6, lane = tid & 63;
    int fm = lane & 15, quad = lane >> 4;
    int ar = tid >> 2, ak = (tid & 3) * 8;         // A staging: row, k-off
    int bn = tid & 63, bk = (tid >> 6) * 8;        // B staging: n, k-off
    const float* w1e = w1 + (size_t)e * 512 * 2048 + ffc0;
    f4_t acc[4] = {{0,0,0,0},{0,0,0,0},{0,0,0,0},{0,0,0,0}};
    for (int k0 = 0; k0 < 512; k0 += 32) {
        // A: gather + convert
        float4 a0 = make_float4(0,0,0,0), a1 = make_float4(0,0,0,0);
        int trow = tok[ar];
        if (trow >= 0) {
            const float4* hp = (const float4*)&h[(size_t)trow * 512 + k0 + ak];
            a0 = hp[0]; a1 = hp[1];
        }
        uint4 pa;
        pa.x = f2bf(a0.x) | ((unsigned)f2bf(a0.y) << 16);
        pa.y = f2bf(a0.z) | ((unsigned)f2bf(a0.w) << 16);
        pa.z = f2bf(a1.x) | ((unsigned)f2bf(a1.y) << 16);
        pa.w = f2bf(a1.z) | ((unsigned)f2bf(a1.w) << 16);
        *(uint4*)&As[ar][ak] = pa;
        // B: strided-k coalesced-n reads + convert (transpose into [n][k])
        float bv[8];
#pragma unroll
        for (int j = 0; j < 8; ++j)
            bv[j] = w1e[(size_t)(k0 + bk + j) * 2048 + n0 + bn];
        uint4 pbk;
        pbk.x = f2bf(bv[0]) | ((unsigned)f2bf(bv[1]) << 16);
        pbk.y = f2bf(bv[2]) | ((unsigned)f2bf(bv[3]) << 16);
        pbk.z = f2bf(bv[4]) | ((unsigned)f2bf(bv[5]) << 16);
        pbk.w = f2bf(bv[6]) | ((unsigned)f2bf(bv[7]) << 16);
        *(uint4*)&Bs[bn][bk] = pbk;
        __syncthreads();
        bf8_t af = *(const bf8_t*)&As[wave * 16 + fm][quad * 8];
#pragma unroll
        for (int t = 0; t < 4; ++t) {
            bf8_t bf = *(const bf8_t*)&Bs[t * 16 + fm][quad * 8];
            acc[t] = __builtin_amdgcn_mfma_f32_16x16x32_bf16(af, bf, acc[t], 0, 0, 0);
        }
        __syncthreads();
    }
    // epilogue: C/D layout col=lane&15, row=quad*4+reg
#pragma unroll
    for (int t = 0; t < 4; ++t) {
#pragma unroll
        for (int r = 0; r < 4; ++r) {
            int ml = wave * 16 + quad * 4 + r;
            int mr = m0 + ml;
            if (mr < segLen) {
                int n = n0 + t * 16 + fm;
                float xv = acc[t][r] + b1[(size_t)e * 2048 + ffc0 + n];
                float gl = 0.5f * xv * (1.f + erff(xv * 0.70710678118654752f));
                hid_bf[(size_t)(segStart + mr) * C_CHUNK + n] = f2bf(gl);
            }
        }
    }
}

// ---------------------------------------------------------------------------
// Expert layer 2 (bf16 MFMA): moe[tok] += gate*(hid_bf @ w2[e][ffc0:+512,:])
// K=512(chunk), N=512. grid (257, 8, E)
// ---------------------------------------------------------------------------
__global__ __launch_bounds__(256) void k_expert2(const unsigned short* __restrict__ hid_bf,
                                                 const float* __restrict__ w2,
                                                 const float* __restrict__ b2,
                                                 const int* __restrict__ offsets,
                                                 const int* __restrict__ tok_list,
                                                 const float* __restrict__ gate_list,
                                                 float* __restrict__ moe,
                                                 int ffc0, int addBias) {
    int e = blockIdx.z;
    int segStart = offsets[e], segEnd = offsets[e + 1];
    int segLen = segEnd - segStart;
    int m0 = blockIdx.x * 64;
    if (m0 >= segLen) return;
    int n0 = blockIdx.y * 64;                      // within d_model [0,512)
    __shared__ unsigned short As[64][40];
    __shared__ unsigned short Bs[64][40];
    __shared__ int tokS[64];
    __shared__ float gateS[64];
    int tid = threadIdx.x;
    if (tid < 64) {
        int mr = m0 + tid;
        tokS[tid]  = (mr < segLen) ? tok_list[segStart + mr] : 0;
        gateS[tid] = (mr < segLen) ? gate_list[segStart + mr] : 0.f;
    }
    __syncthreads();
    int wave = tid >> 6, lane = tid & 63;
    int fm = lane & 15, quad = lane >> 4;
    int ar = tid >> 2, ak = (tid & 3) * 8;
    int bn = tid & 63, bk = (tid >> 6) * 8;
    const float* w2e = w2 + (size_t)e * 2048 * 512 + (size_t)ffc0 * 512;
    f4_t acc[4] = {{0,0,0,0},{0,0,0,0},{0,0,0,0},{0,0,0,0}};
    for (int k0 = 0; k0 < C_CHUNK; k0 += 32) {
        // A: hid_bf rows are contiguous slots (no gather), already bf16
        uint4 pa = make_uint4(0, 0, 0, 0);
        if (m0 + ar < segLen)
            pa = *(const uint4*)&hid_bf[(size_t)(segStart + m0 + ar) * C_CHUNK + k0 + ak];
        *(uint4*)&As[ar][ak] = pa;
        // B: w2 f32 -> bf16, transpose into [n][k]
        float bv[8];
#pragma unroll
        for (int j = 0; j < 8; ++j)
            bv[j] = w2e[(size_t)(k0 + bk + j) * 512 + n0 + bn];
        uint4 pbk;
        pbk.x = f2bf(bv[0]) | ((unsigned)f2bf(bv[1]) << 16);
        pbk.y = f2bf(bv[2]) | ((unsigned)f2bf(bv[3]) << 16);
        pbk.z = f2bf(bv[4]) | ((unsigned)f2bf(bv[5]) << 16);
        pbk.w = f2bf(bv[6]) | ((unsigned)f2bf(bv[7]) << 16);
        *(uint4*)&Bs[bn][bk] = pbk;
        __syncthreads();
        bf8_t af = *(const bf8_t*)&As[wave * 16 + fm][quad * 8];
#pragma unroll
        for (int t = 0; t < 4; ++t) {
            bf8_t bf = *(const bf8_t*)&Bs[t * 16 + fm][quad * 8];
            acc[t] = __builtin_amdgcn_mfma_f32_16x16x32_bf16(af, bf, acc[t], 0, 0, 0);
        }
        __syncthreads();
    }
#pragma unroll
    for (int t = 0; t < 4; ++t) {
#pragma unroll
        for (int r = 0; r < 4; ++r) {
            int ml = wave * 16 + quad * 4 + r;
            int mr = m0 + ml;
            if (mr < segLen) {
                int n = n0 + t * 16 + fm;
                float v = acc[t][r];
                if (addBias) v += b2[(size_t)e * 512 + n];
                atomicAdd(&moe[(size_t)tokS[ml] * 512 + n], gateS[ml] * v);
            }
        }
    }
}

// ---------------------------------------------------------------------------
// LayerNorm(d=512) + affine + residual.
// ---------------------------------------------------------------------------
__device__ __forceinline__ float block_sum512(float v, float* red, int tid) {
#pragma unroll
    for (int off = 32; off > 0; off >>= 1) v += __shfl_xor(v, off);
    __syncthreads();
    if ((tid & 63) == 0) red[tid >> 6] = v;
    __syncthreads();
    return red[0] + red[1] + red[2] + red[3];
}

__global__ __launch_bounds__(256) void k_ln(const float* __restrict__ ot,
                                            const float* __restrict__ x,
                                            const float* __restrict__ g,
                                            const float* __restrict__ bb,
                                            float* __restrict__ out) {
    __shared__ float red[4];
    int t = blockIdx.x;
    int tid = threadIdx.x;
    const float* row = ot + (size_t)t * 512;
    float v0 = row[tid], v1 = row[tid + 256];
    float total = block_sum512(v0 + v1, red, tid);
    float mu = total * (1.f / 512.f);
    float q0 = v0 - mu, q1 = v1 - mu;
    float var = block_sum512(q0 * q0 + q1 * q1, red, tid) * (1.f / 512.f);
    float rstd = rsqrtf(var + 1e-5f);
    const float* xr = x + (size_t)t * 512;
    float* orow = out + (size_t)t * 512;
    orow[tid]       = q0 * rstd * g[tid]       + bb[tid]       + xr[tid];
    orow[tid + 256] = q1 * rstd * g[tid + 256] + bb[tid + 256] + xr[tid + 256];
}

// ---------------------------------------------------------------------------
// ws (floats): Y=[0:2*TOKD) = yf (padded) -> (moe f32 | hid bf16) -> ot.
// T1=[2TOKD:2TOKD+PB) of_b; T2=[+PB] ofT_b.
// d_out: phase1 xt (dead after fft); then h + routing lists + Wr/br;
// phase7 otT; LN overwrites.
// ---------------------------------------------------------------------------
extern "C" void kernel_launch(void* const* d_in, const int* in_sizes, int n_in,
                              void* d_out, int out_size, void* d_ws, size_t ws_size,
                              hipStream_t stream) {
    const float* x        = (const float*)d_in[0];
    const float* pin_w    = (const float*)d_in[1];
    const float* pin_b    = (const float*)d_in[2];
    const float* router_w = (const float*)d_in[3];
    const float* router_b = (const float*)d_in[4];
    const float* w1       = (const float*)d_in[5];
    const float* b1       = (const float*)d_in[6];
    const float* w2       = (const float*)d_in[7];
    const float* b2       = (const float*)d_in[8];
    const float* pout_w   = (const float*)d_in[9];
    const float* pout_b   = (const float*)d_in[10];
    const float* ln_g     = (const float*)d_in[11];
    const float* ln_b     = (const float*)d_in[12];
    float* outf = (float*)d_out;

    float* Y   = (float*)d_ws;                    // yf; later moe|hid; later ot
    float* moe = Y;                               // (NTOK,512) f32
    unsigned short* hid_bf = (unsigned short*)(Y + C_TOKD);  // (NSLOT,512) bf16
    float* T1  = Y + 2 * C_TOKD;                  // of_b (F,1024)
    float* T2  = T1 + C_PB;                       // ofT_b (1024,F)
    float* ot  = Y;                               // (B,S,D) final pre-LN

    float* xt    = outf;                          // (B,D,S)
    float* h     = outf;                          // (NTOK,512)
    float* topkw = outf + C_TOKD;
    float* gate  = topkw + C_NSLOT;
    int* topki   = (int*)(gate + C_NSLOT);
    int* tokl    = topki + C_NSLOT;
    int* counts  = tokl + C_NSLOT;                       // padded: 8*16 ints
    int* cursor  = counts + C_E * C_CSTRIDE;             // padded: 8*16 ints
    int* offsets = cursor + C_E * C_CSTRIDE;             // 9 ints
    float* wrbuf = outf + C_TOKD + (size_t)6 * C_NSLOT;  // (1024,8) fused Wr
    float* brbuf = wrbuf + 1024 * 8;                     // (8)
    float* otT   = outf;                          // (B,D,S)

    dim3 tb(32, 8);
    // 1. x (B,S,D) -> xt (B,D,S)
    k_transpose<<<dim3(C_D / 32, C_SEQ / 32, C_B), tb, 0, stream>>>(x, xt, C_SEQ, C_D);
    // 2. rfft (padded yf rows); xt dead afterwards
    k_fft_fwd<<<C_B * C_D, 256, 0, stream>>>(xt, Y);
    // 3. fused router weights (f32 exact) + counter zero
    k_wr<<<32, 256, 0, stream>>>(pin_w, pin_b, router_w, router_b, wrbuf, brbuf);
    k_zero<<<4, 64, 0, stream>>>(counts, 2 * C_E * C_CSTRIDE);
    // 4. routing straight from yf (f32)
    k_router2<<<dim3((C_FREQ + 255) / 256, C_B), 256, 0, stream>>>(
        Y, wrbuf, brbuf, topki, topkw, counts);
    k_scan<<<1, 64, 0, stream>>>(counts, offsets, cursor);
    k_fill<<<(C_NTOK + 255) / 256, 256, 0, stream>>>(topki, topkw, cursor, tokl, gate);
    // 5. pin projection (bf16 MFMA) — h feeds experts only
    k_pin_mfma<<<dim3(33, 8, C_B), 256, 0, stream>>>(Y, pin_w, pin_b, h);
    // 6. moe zero AFTER pin (moe aliases yf region) — kernel, not memset
    k_zerof<<<2048, 256, 0, stream>>>(moe, (unsigned long long)C_TOKD);
    // 7. grouped expert MLP, bf16 MFMA (d_ff chunked by 512)
    for (int c = 0; c < C_NCHUNK; ++c) {
        int ffc0 = c * C_CHUNK;
        k_expert1<<<dim3(257, 8, C_E), 256, 0, stream>>>(
            h, w1, b1, offsets, tokl, hid_bf, ffc0);
        k_expert2<<<dim3(257, 8, C_E), 256, 0, stream>>>(
            hid_bf, w2, b2, offsets, tokl, gate, moe, ffc0, c == 0 ? 1 : 0);
    }
    // 8. per batch: pout (bf16 MFMA) -> of_b, transpose, irfft -> otT
    for (int b = 0; b < C_B; ++b) {
        const float* moeb = moe + (size_t)b * C_FREQ * 512;
        k_pout_mfma<<<dim3(33, 16), 256, 0, stream>>>(moeb, pout_w, pout_b, T1);
        k_transpose<<<dim3(1024 / 32, (C_FREQ + 31) / 32, 1), tb, 0, stream>>>(
            T1, T2, C_FREQ, 1024);
        k_fft_inv<<<C_D, 256, 0, stream>>>(T2, otT + (size_t)b * C_D * C_SEQ);
    }
    // 9. otT -> ot (B,S,D) in ws
    k_transpose<<<dim3(C_SEQ / 32, C_D / 32, C_B), tb, 0, stream>>>(otT, ot, C_D, C_SEQ);
    // 10. LN + residual
    k_ln<<<C_B * C_SEQ, 256, 0, stream>>>(ot, x, ln_g, ln_b, outf);
}

// Round 7
// 1570.847 us; speedup vs baseline: 1.4361x; 1.1287x over previous
//
#include <hip/hip_runtime.h>
#include <math.h>

#define PI_F 3.14159265358979323846f

// Problem sizes
#define C_SEQ   4096
#define C_B     8
#define C_D     512
#define C_FREQ  2049                  // SEQ/2+1
#define C_FPAD  2052                  // yf row stride (padded)
#define C_NTOK  (C_B * C_FREQ)        // 16392
#define C_NSLOT (2 * C_NTOK)          // 32784
#define C_CHUNK 512                   // d_ff chunk (hid is bf16)
#define C_NCHUNK 4
#define C_E     8
#define C_TOKD  ((size_t)C_NTOK * 512)   // 8,392,704 floats
#define C_PB    ((size_t)C_FREQ * 1024)  // 2,098,176 floats (one batch F-slab)
#define C_CSTRIDE 16                  // counter padding: 16 ints = 64B cacheline

typedef __attribute__((ext_vector_type(8))) short bf8_t;   // 8 bf16 (4 VGPRs)
typedef __attribute__((ext_vector_type(4))) float f4_t;    // MFMA acc

__device__ __forceinline__ unsigned short f2bf(float f) {
    union { float f; unsigned u; } v; v.f = f;
    unsigned r = v.u + 0x7FFF + ((v.u >> 16) & 1);   // RNE
    return (unsigned short)(r >> 16);
}

// ---------------------------------------------------------------------------
// Transpose: in (Z, R, C) -> out (Z, C, R); grid (ceil(C/32), ceil(R/32), Z)
// ---------------------------------------------------------------------------
__global__ __launch_bounds__(256) void k_transpose(const float* __restrict__ in,
                                                   float* __restrict__ out,
                                                   int R, int C) {
    __shared__ float t[32][33];
    int c0 = blockIdx.x * 32, r0 = blockIdx.y * 32;
    const float* inb = in + (size_t)blockIdx.z * R * C;
    float* outb = out + (size_t)blockIdx.z * R * C;
    int tx = threadIdx.x, ty = threadIdx.y;
#pragma unroll
    for (int i = 0; i < 4; ++i) {
        int r = r0 + ty + i * 8, c = c0 + tx;
        if (r < R && c < C) t[ty + i * 8][tx] = inb[(size_t)r * C + c];
    }
    __syncthreads();
#pragma unroll
    for (int i = 0; i < 4; ++i) {
        int c = c0 + ty + i * 8, r = r0 + tx;
        if (r < R && c < C) outb[(size_t)c * R + r] = t[tx][ty + i * 8];
    }
}

// ---------------------------------------------------------------------------
// 4096-pt in-place radix-2 DIT FFT in LDS.
// SW(): XOR bank-swizzle — folds addr bits 6-10 into bank bits. Fixes the
// stride-64 bit-reversal scatter (was 64 lanes -> 1 bank) and stage 1;
// stages 2-5 remain ~4-way (acceptable). Twiddles from a 2048-entry LDS
// table (built once per block: 8 sincos/thread vs 96 before).
// ---------------------------------------------------------------------------
#define SW(i) ((i) ^ (((i) >> 6) & 31))

__device__ __forceinline__ int brev12(int x) {
    return (int)(__brev((unsigned)x) >> 20);
}

__device__ __forceinline__ void fft_twiddle_init(float* twr, float* twi, int tid) {
#pragma unroll
    for (int q = 0; q < 8; ++q) {
        int k = tid + q * 256;                      // 0..2047
        float sn, cs;
        __sincosf(-PI_F * (float)k / 2048.f, &sn, &cs);   // -2*pi*k/4096
        int a = SW(k);
        twr[a] = cs; twi[a] = sn;
    }
}

__device__ __forceinline__ void fft4096_inplace(float* re, float* im,
                                                const float* twr, const float* twi,
                                                int tid) {
    for (int s = 1; s <= 12; ++s) {
        int half = 1 << (s - 1);
        int shift = 12 - s;
        __syncthreads();
#pragma unroll
        for (int u = 0; u < 8; ++u) {
            int bf = tid + u * 256;                 // 0..2047
            int j = bf & (half - 1);
            int i1 = ((bf >> (s - 1)) << s) + j;
            int i2 = i1 + half;
            int a1 = SW(i1), a2 = SW(i2);
            int tw = SW(j << shift);
            float cs = twr[tw], sn = twi[tw];
            float ur = re[a1], ui = im[a1];
            float vr = re[a2], vi = im[a2];
            float tr = vr * cs - vi * sn;
            float ti = vr * sn + vi * cs;
            re[a1] = ur + tr; im[a1] = ui + ti;
            re[a2] = ur - tr; im[a2] = ui - ti;
        }
    }
    __syncthreads();
}

// rfft(ortho): xt (B, D, S) -> yf (B, 1024, FPAD)  rows: c=d real, c=512+d imag
__global__ __launch_bounds__(256) void k_fft_fwd(const float* __restrict__ xt,
                                                 float* __restrict__ yf) {
    __shared__ float re[4096], im[4096], twr[2048], twi[2048];
    int tid = threadIdx.x;
    int sig = blockIdx.x;
    int b = sig >> 9, d = sig & 511;
    fft_twiddle_init(twr, twi, tid);
    const float* src = xt + ((size_t)b * C_D + d) * C_SEQ;
    for (int i = tid; i < 4096; i += 256) {
        int r = SW(brev12(i));
        re[r] = src[i];
        im[r] = 0.f;
    }
    fft4096_inplace(re, im, twr, twi, tid);
    float* outRe = yf + ((size_t)b * 1024 + d) * C_FPAD;
    float* outIm = yf + ((size_t)b * 1024 + 512 + d) * C_FPAD;
    const float scale = 1.f / 64.f;                // 1/sqrt(4096)
    for (int k = tid; k < C_FPAD; k += 256) {
        int a = SW(k);
        float vr = (k < C_FREQ) ? re[a] * scale : 0.f;
        float vi = (k < C_FREQ) ? im[a] * scale : 0.f;
        outRe[k] = vr;
        outIm[k] = vi;
    }
}

// irfft(ortho), TWO batches per launch: ofTpair (2,1024,F) -> otT slabs.
// grid 1024: sub = blockIdx.x>>9 selects slab, d = blockIdx.x&511.
__global__ __launch_bounds__(256) void k_fft_inv(const float* __restrict__ ofTpair,
                                                 float* __restrict__ otTpair) {
    __shared__ float re[4096], im[4096], twr[2048], twi[2048];
    int tid = threadIdx.x;
    int sub = blockIdx.x >> 9;
    int d = blockIdx.x & 511;
    fft_twiddle_init(twr, twi, tid);
    const float* inRe = ofTpair + (size_t)sub * C_PB + (size_t)d * C_FREQ;
    const float* inIm = ofTpair + (size_t)sub * C_PB + (size_t)(512 + d) * C_FREQ;
    for (int i = tid; i < 4096; i += 256) {
        float zr, zi;
        if (i <= 2048) { zr = inRe[i];        zi = -inIm[i]; }
        else           { zr = inRe[4096 - i]; zi =  inIm[4096 - i]; }
        int r = SW(brev12(i));
        re[r] = zr;
        im[r] = zi;
    }
    fft4096_inplace(re, im, twr, twi, tid);
    float* dst = otTpair + (size_t)sub * C_D * C_SEQ + (size_t)d * C_SEQ;
    const float scale = 1.f / 64.f;
    for (int n = tid; n < 4096; n += 256) dst[n] = re[SW(n)] * scale;
}

// ---------------------------------------------------------------------------
// pin GEMM, bf16 MFMA: h[b,f,:] = yf[b]^T @ pin_w + pin_b.
// 64x64 tile, BK=32, 4 waves. grid (33, 8, B)
// ---------------------------------------------------------------------------
__global__ __launch_bounds__(256) void k_pin_mfma(const float* __restrict__ yf,
                                                  const float* __restrict__ pw,
                                                  const float* __restrict__ pb,
                                                  float* __restrict__ h) {
    int b = blockIdx.z;
    int m0 = blockIdx.x * 64;                      // f
    int n0 = blockIdx.y * 64;                      // out feature
    __shared__ unsigned short As[64][40];          // [m][k]
    __shared__ unsigned short Bs[64][40];          // [n][k]
    int tid = threadIdx.x;
    int wave = tid >> 6, lane = tid & 63;
    int fm = lane & 15, quad = lane >> 4;
    int sn = tid & 63, sk = (tid >> 6) * 8;        // staging: row, k-offset
    const float* Ab = yf + (size_t)b * 1024 * C_FPAD;
    bool mvalid = (m0 + sn) < C_FREQ;
    f4_t acc[4] = {{0,0,0,0},{0,0,0,0},{0,0,0,0},{0,0,0,0}};
    for (int k0 = 0; k0 < 1024; k0 += 32) {
        // A: strided-k coalesced-m reads (k-major source), pack -> [m][k]
        float av[8];
#pragma unroll
        for (int j = 0; j < 8; ++j)
            av[j] = mvalid ? Ab[(size_t)(k0 + sk + j) * C_FPAD + m0 + sn] : 0.f;
        uint4 pa;
        pa.x = f2bf(av[0]) | ((unsigned)f2bf(av[1]) << 16);
        pa.y = f2bf(av[2]) | ((unsigned)f2bf(av[3]) << 16);
        pa.z = f2bf(av[4]) | ((unsigned)f2bf(av[5]) << 16);
        pa.w = f2bf(av[6]) | ((unsigned)f2bf(av[7]) << 16);
        *(uint4*)&As[sn][sk] = pa;
        // B: same pattern, stride 512
        float bv[8];
#pragma unroll
        for (int j = 0; j < 8; ++j)
            bv[j] = pw[(size_t)(k0 + sk + j) * 512 + n0 + sn];
        uint4 pbk;
        pbk.x = f2bf(bv[0]) | ((unsigned)f2bf(bv[1]) << 16);
        pbk.y = f2bf(bv[2]) | ((unsigned)f2bf(bv[3]) << 16);
        pbk.z = f2bf(bv[4]) | ((unsigned)f2bf(bv[5]) << 16);
        pbk.w = f2bf(bv[6]) | ((unsigned)f2bf(bv[7]) << 16);
        *(uint4*)&Bs[sn][sk] = pbk;
        __syncthreads();
        bf8_t af = *(const bf8_t*)&As[wave * 16 + fm][quad * 8];
#pragma unroll
        for (int t = 0; t < 4; ++t) {
            bf8_t bf = *(const bf8_t*)&Bs[t * 16 + fm][quad * 8];
            acc[t] = __builtin_amdgcn_mfma_f32_16x16x32_bf16(af, bf, acc[t], 0, 0, 0);
        }
        __syncthreads();
    }
    // epilogue: C/D layout col=lane&15, row=quad*4+reg
#pragma unroll
    for (int t = 0; t < 4; ++t) {
#pragma unroll
        for (int r = 0; r < 4; ++r) {
            int m = m0 + wave * 16 + quad * 4 + r;
            if (m < C_FREQ) {
                int n = n0 + t * 16 + fm;
                h[((size_t)b * C_FREQ + m) * 512 + n] = acc[t][r] + pb[n];
            }
        }
    }
}

// ---------------------------------------------------------------------------
// pout GEMM, bf16 MFMA, TWO batches per launch: of = moe_b @ pout_w + pout_b
// (F,512)x(512,1024). grid (33, 16, 2); z selects batch b0+z, slab z*PB.
// ---------------------------------------------------------------------------
__global__ __launch_bounds__(256) void k_pout_mfma(const float* __restrict__ moe,
                                                   const float* __restrict__ pw,
                                                   const float* __restrict__ pb,
                                                   float* __restrict__ ofpair,
                                                   int b0) {
    int z = blockIdx.z;
    const float* moeb = moe + (size_t)(b0 + z) * C_FREQ * 512;
    float* ofb = ofpair + (size_t)z * C_PB;
    int m0 = blockIdx.x * 64;                      // f
    int n0 = blockIdx.y * 64;                      // out col of 1024
    __shared__ unsigned short As[64][40];
    __shared__ unsigned short Bs[64][40];
    int tid = threadIdx.x;
    int wave = tid >> 6, lane = tid & 63;
    int fm = lane & 15, quad = lane >> 4;
    int ar = tid >> 2, ak = (tid & 3) * 8;         // A: row, k-off
    int bn = tid & 63, bk = (tid >> 6) * 8;        // B: n, k-off
    bool avalid = (m0 + ar) < C_FREQ;
    f4_t acc[4] = {{0,0,0,0},{0,0,0,0},{0,0,0,0},{0,0,0,0}};
    for (int k0 = 0; k0 < 512; k0 += 32) {
        // A: row-major f32 -> bf16 [m][k]
        float4 a0 = make_float4(0,0,0,0), a1 = make_float4(0,0,0,0);
        if (avalid) {
            const float4* ap = (const float4*)&moeb[(size_t)(m0 + ar) * 512 + k0 + ak];
            a0 = ap[0]; a1 = ap[1];
        }
        uint4 pa;
        pa.x = f2bf(a0.x) | ((unsigned)f2bf(a0.y) << 16);
        pa.y = f2bf(a0.z) | ((unsigned)f2bf(a0.w) << 16);
        pa.z = f2bf(a1.x) | ((unsigned)f2bf(a1.y) << 16);
        pa.w = f2bf(a1.z) | ((unsigned)f2bf(a1.w) << 16);
        *(uint4*)&As[ar][ak] = pa;
        // B: strided-k coalesced-n (stride 1024), pack -> [n][k]
        float bv[8];
#pragma unroll
        for (int j = 0; j < 8; ++j)
            bv[j] = pw[(size_t)(k0 + bk + j) * 1024 + n0 + bn];
        uint4 pbk;
        pbk.x = f2bf(bv[0]) | ((unsigned)f2bf(bv[1]) << 16);
        pbk.y = f2bf(bv[2]) | ((unsigned)f2bf(bv[3]) << 16);
        pbk.z = f2bf(bv[4]) | ((unsigned)f2bf(bv[5]) << 16);
        pbk.w = f2bf(bv[6]) | ((unsigned)f2bf(bv[7]) << 16);
        *(uint4*)&Bs[bn][bk] = pbk;
        __syncthreads();
        bf8_t af = *(const bf8_t*)&As[wave * 16 + fm][quad * 8];
#pragma unroll
        for (int t = 0; t < 4; ++t) {
            bf8_t bf = *(const bf8_t*)&Bs[t * 16 + fm][quad * 8];
            acc[t] = __builtin_amdgcn_mfma_f32_16x16x32_bf16(af, bf, acc[t], 0, 0, 0);
        }
        __syncthreads();
    }
#pragma unroll
    for (int t = 0; t < 4; ++t) {
#pragma unroll
        for (int r = 0; r < 4; ++r) {
            int m = m0 + wave * 16 + quad * 4 + r;
            if (m < C_FREQ) {
                int n = n0 + t * 16 + fm;
                ofb[(size_t)m * 1024 + n] = acc[t][r] + pb[n];
            }
        }
    }
}

__global__ void k_zero(int* p, int n) {
    int i = blockIdx.x * 64 + threadIdx.x;
    if (i < n) p[i] = 0;
}

// grid-stride f32 zero (NOT hipMemsetAsync — graph-capture safe)
__global__ __launch_bounds__(256) void k_zerof(float* __restrict__ p, unsigned long long n) {
    unsigned long long i = (unsigned long long)blockIdx.x * 256 + threadIdx.x;
    unsigned long long stride = (unsigned long long)gridDim.x * 256;
    for (; i < n; i += stride) p[i] = 0.f;
}

// ---------------------------------------------------------------------------
// Fused router weights (f32, exact): Wr = pin_w @ router_w  (1024 x 8),
// br = pin_b @ router_w + router_b. grid (32) x 256: thread=(k,e).
// ---------------------------------------------------------------------------
__global__ __launch_bounds__(256) void k_wr(const float* __restrict__ pin_w,
                                            const float* __restrict__ pin_b,
                                            const float* __restrict__ rw,
                                            const float* __restrict__ rb,
                                            float* __restrict__ wr,
                                            float* __restrict__ brv) {
    int k = blockIdx.x * 32 + (threadIdx.x >> 3);
    int e = threadIdx.x & 7;
    const float* pr = &pin_w[(size_t)k * 512];
    float s = 0.f;
    for (int d = 0; d < 512; ++d) s += pr[d] * rw[d * 8 + e];
    wr[k * 8 + e] = s;
    if (blockIdx.x == 0 && threadIdx.x < 8) {
        float s2 = 0.f;
        for (int d = 0; d < 512; ++d) s2 += pin_b[d] * rw[d * 8 + e];
        brv[e] = s2 + rb[e];
    }
}

// ---------------------------------------------------------------------------
// Router v5: split-K x4 for occupancy (was 72 blocks ~1 wave/CU).
// Block = 64 tokens x 4 k-quarters; LDS partials (+1 pad), 1 wave finishes.
// grid (33, B).
// ---------------------------------------------------------------------------
__global__ __launch_bounds__(256) void k_router2(const float* __restrict__ yf,
                                                 const float* __restrict__ wr,
                                                 const float* __restrict__ brv,
                                                 int* __restrict__ topk_idx,
                                                 float* __restrict__ topk_w,
                                                 int* __restrict__ counts) {
    __shared__ float part[4][64][9];               // +1 pad: stride 9 coprime 32
    __shared__ int lc[C_E];
    int tid = threadIdx.x;
    int lane = tid & 63, kq = tid >> 6;
    if (tid < C_E) lc[tid] = 0;
    int b = blockIdx.y;
    int f = blockIdx.x * 64 + lane;
    bool valid = (f < C_FREQ);
    int fc = valid ? f : (C_FREQ - 1);
    const float* Ab = yf + (size_t)b * 1024 * C_FPAD + fc;
    float lg[8] = {};
    int kbeg = kq * 256;
#pragma unroll 4
    for (int k = kbeg; k < kbeg + 256; ++k) {
        float a = Ab[(size_t)k * C_FPAD];          // coalesced across lanes
        const float* w = &wr[k * 8];               // wave-uniform -> s_load
#pragma unroll
        for (int e = 0; e < 8; ++e) lg[e] += a * w[e];
    }
#pragma unroll
    for (int e = 0; e < 8; ++e) part[kq][lane][e] = lg[e];
    __syncthreads();
    if (tid < 64 && (blockIdx.x * 64 + tid) < C_FREQ) {
        int ff = blockIdx.x * 64 + tid;
        float v[8];
#pragma unroll
        for (int e = 0; e < 8; ++e)
            v[e] = part[0][tid][e] + part[1][tid][e] + part[2][tid][e]
                 + part[3][tid][e] + brv[e];
        int i1 = 0;
        for (int q = 1; q < 8; ++q) if (v[q] > v[i1]) i1 = q;
        int i2 = -1;
        for (int q = 0; q < 8; ++q)
            if (q != i1 && (i2 < 0 || v[q] > v[i2])) i2 = q;
        float w1 = 1.f / (1.f + __expf(v[i2] - v[i1]));
        int t = b * C_FREQ + ff;
        topk_idx[t * 2] = i1; topk_idx[t * 2 + 1] = i2;
        topk_w[t * 2] = w1;   topk_w[t * 2 + 1] = 1.f - w1;
        atomicAdd(&lc[i1], 1);
        atomicAdd(&lc[i2], 1);
    }
    __syncthreads();
    if (tid < C_E) {
        int c = lc[tid];
        if (c > 0) atomicAdd(&counts[tid * C_CSTRIDE], c);
    }
}

__global__ void k_scan(const int* __restrict__ counts, int* __restrict__ offsets,
                       int* __restrict__ cursor) {
    if (threadIdx.x == 0) {
        int acc = 0;
        for (int e = 0; e < C_E; ++e) {
            offsets[e] = acc;
            cursor[e * C_CSTRIDE] = acc;
            acc += counts[e * C_CSTRIDE];
        }
        offsets[C_E] = acc;
    }
}

// ---------------------------------------------------------------------------
// Fill: block-level two-phase reservation (LDS histogram + rank, one
// padded global atomic per expert per block, conflict-free scatter).
// ---------------------------------------------------------------------------
__global__ __launch_bounds__(256) void k_fill(const int* __restrict__ topk_idx,
                                              const float* __restrict__ topk_w,
                                              int* __restrict__ cursor,
                                              int* __restrict__ tok_list,
                                              float* __restrict__ gate_list) {
    __shared__ int lc[C_E];
    __shared__ int lbase[C_E];
    int tid = threadIdx.x;
    if (tid < C_E) lc[tid] = 0;
    __syncthreads();
    int t = blockIdx.x * 256 + tid;
    int e0 = 0, e1 = 0, p0 = 0, p1 = 0;
    float w0 = 0.f, w1 = 0.f;
    bool valid = (t < C_NTOK);
    if (valid) {
        e0 = topk_idx[t * 2];     e1 = topk_idx[t * 2 + 1];
        w0 = topk_w[t * 2];       w1 = topk_w[t * 2 + 1];
        p0 = atomicAdd(&lc[e0], 1);
        p1 = atomicAdd(&lc[e1], 1);
    }
    __syncthreads();
    if (tid < C_E) {
        int c = lc[tid];
        lbase[tid] = (c > 0) ? atomicAdd(&cursor[tid * C_CSTRIDE], c) : 0;
    }
    __syncthreads();
    if (valid) {
        int pos0 = lbase[e0] + p0;
        tok_list[pos0] = t; gate_list[pos0] = w0;
        int pos1 = lbase[e1] + p1;
        tok_list[pos1] = t; gate_list[pos1] = w1;
    }
}

// ---------------------------------------------------------------------------
// Expert layer 1 (bf16 MFMA): hid_bf[slot] = gelu(h[tok] @ w1[e][:,ffc0:+512])
// Tile 64x64, BK=32, 4 waves. grid (257, 8, E)
// ---------------------------------------------------------------------------
__global__ __launch_bounds__(256) void k_expert1(const float* __restrict__ h,
                                                 const float* __restrict__ w1,
                                                 const float* __restrict__ b1,
                                                 const int* __restrict__ offsets,
                                                 const int* __restrict__ tok_list,
                                                 unsigned short* __restrict__ hid_bf,
                                                 int ffc0) {
    int e = blockIdx.z;
    int segStart = offsets[e], segEnd = offsets[e + 1];
    int segLen = segEnd - segStart;
    int m0 = blockIdx.x * 64;
    if (m0 >= segLen) return;
    int n0 = blockIdx.y * 64;                      // within chunk [0,512)
    __shared__ unsigned short As[64][40];          // [m][k] pad->80B rows
    __shared__ unsigned short Bs[64][40];          // [n][k]
    __shared__ int tok[64];
    int tid = threadIdx.x;
    if (tid < 64) {
        int mr = m0 + tid;
        tok[tid] = (mr < segLen) ? tok_list[segStart + mr] : -1;
    }
    __syncthreads();
    int wave = tid >> 6, lane = tid & 63;
    int fm = lane & 15, quad = lane >> 4;
    int ar = tid >> 2, ak = (tid & 3) * 8;         // A staging: row, k-off
    int bn = tid & 63, bk = (tid >> 6) * 8;        // B staging: n, k-off
    const float* w1e = w1 + (size_t)e * 512 * 2048 + ffc0;
    f4_t acc[4] = {{0,0,0,0},{0,0,0,0},{0,0,0,0},{0,0,0,0}};
    for (int k0 = 0; k0 < 512; k0 += 32) {
        // A: gather + convert
        float4 a0 = make_float4(0,0,0,0), a1 = make_float4(0,0,0,0);
        int trow = tok[ar];
        if (trow >= 0) {
            const float4* hp = (const float4*)&h[(size_t)trow * 512 + k0 + ak];
            a0 = hp[0]; a1 = hp[1];
        }
        uint4 pa;
        pa.x = f2bf(a0.x) | ((unsigned)f2bf(a0.y) << 16);
        pa.y = f2bf(a0.z) | ((unsigned)f2bf(a0.w) << 16);
        pa.z = f2bf(a1.x) | ((unsigned)f2bf(a1.y) << 16);
        pa.w = f2bf(a1.z) | ((unsigned)f2bf(a1.w) << 16);
        *(uint4*)&As[ar][ak] = pa;
        // B: strided-k coalesced-n reads + convert (transpose into [n][k])
        float bv[8];
#pragma unroll
        for (int j = 0; j < 8; ++j)
            bv[j] = w1e[(size_t)(k0 + bk + j) * 2048 + n0 + bn];
        uint4 pbk;
        pbk.x = f2bf(bv[0]) | ((unsigned)f2bf(bv[1]) << 16);
        pbk.y = f2bf(bv[2]) | ((unsigned)f2bf(bv[3]) << 16);
        pbk.z = f2bf(bv[4]) | ((unsigned)f2bf(bv[5]) << 16);
        pbk.w = f2bf(bv[6]) | ((unsigned)f2bf(bv[7]) << 16);
        *(uint4*)&Bs[bn][bk] = pbk;
        __syncthreads();
        bf8_t af = *(const bf8_t*)&As[wave * 16 + fm][quad * 8];
#pragma unroll
        for (int t = 0; t < 4; ++t) {
            bf8_t bf = *(const bf8_t*)&Bs[t * 16 + fm][quad * 8];
            acc[t] = __builtin_amdgcn_mfma_f32_16x16x32_bf16(af, bf, acc[t], 0, 0, 0);
        }
        __syncthreads();
    }
    // epilogue: C/D layout col=lane&15, row=quad*4+reg
#pragma unroll
    for (int t = 0; t < 4; ++t) {
#pragma unroll
        for (int r = 0; r < 4; ++r) {
            int ml = wave * 16 + quad * 4 + r;
            int mr = m0 + ml;
            if (mr < segLen) {
                int n = n0 + t * 16 + fm;
                float xv = acc[t][r] + b1[(size_t)e * 2048 + ffc0 + n];
                float gl = 0.5f * xv * (1.f + erff(xv * 0.70710678118654752f));
                hid_bf[(size_t)(segStart + mr) * C_CHUNK + n] = f2bf(gl);
            }
        }
    }
}

// ---------------------------------------------------------------------------
// Expert layer 2 (bf16 MFMA): moe[tok] += gate*(hid_bf @ w2[e][ffc0:+512,:])
// K=512(chunk), N=512. grid (257, 8, E)
// ---------------------------------------------------------------------------
__global__ __launch_bounds__(256) void k_expert2(const unsigned short* __restrict__ hid_bf,
                                                 const float* __restrict__ w2,
                                                 const float* __restrict__ b2,
                                                 const int* __restrict__ offsets,
                                                 const int* __restrict__ tok_list,
                                                 const float* __restrict__ gate_list,
                                                 float* __restrict__ moe,
                                                 int ffc0, int addBias) {
    int e = blockIdx.z;
    int segStart = offsets[e], segEnd = offsets[e + 1];
    int segLen = segEnd - segStart;
    int m0 = blockIdx.x * 64;
    if (m0 >= segLen) return;
    int n0 = blockIdx.y * 64;                      // within d_model [0,512)
    __shared__ unsigned short As[64][40];
    __shared__ unsigned short Bs[64][40];
    __shared__ int tokS[64];
    __shared__ float gateS[64];
    int tid = threadIdx.x;
    if (tid < 64) {
        int mr = m0 + tid;
        tokS[tid]  = (mr < segLen) ? tok_list[segStart + mr] : 0;
        gateS[tid] = (mr < segLen) ? gate_list[segStart + mr] : 0.f;
    }
    __syncthreads();
    int wave = tid >> 6, lane = tid & 63;
    int fm = lane & 15, quad = lane >> 4;
    int ar = tid >> 2, ak = (tid & 3) * 8;
    int bn = tid & 63, bk = (tid >> 6) * 8;
    const float* w2e = w2 + (size_t)e * 2048 * 512 + (size_t)ffc0 * 512;
    f4_t acc[4] = {{0,0,0,0},{0,0,0,0},{0,0,0,0},{0,0,0,0}};
    for (int k0 = 0; k0 < C_CHUNK; k0 += 32) {
        // A: hid_bf rows are contiguous slots (no gather), already bf16
        uint4 pa = make_uint4(0, 0, 0, 0);
        if (m0 + ar < segLen)
            pa = *(const uint4*)&hid_bf[(size_t)(segStart + m0 + ar) * C_CHUNK + k0 + ak];
        *(uint4*)&As[ar][ak] = pa;
        // B: w2 f32 -> bf16, transpose into [n][k]
        float bv[8];
#pragma unroll
        for (int j = 0; j < 8; ++j)
            bv[j] = w2e[(size_t)(k0 + bk + j) * 512 + n0 + bn];
        uint4 pbk;
        pbk.x = f2bf(bv[0]) | ((unsigned)f2bf(bv[1]) << 16);
        pbk.y = f2bf(bv[2]) | ((unsigned)f2bf(bv[3]) << 16);
        pbk.z = f2bf(bv[4]) | ((unsigned)f2bf(bv[5]) << 16);
        pbk.w = f2bf(bv[6]) | ((unsigned)f2bf(bv[7]) << 16);
        *(uint4*)&Bs[bn][bk] = pbk;
        __syncthreads();
        bf8_t af = *(const bf8_t*)&As[wave * 16 + fm][quad * 8];
#pragma unroll
        for (int t = 0; t < 4; ++t) {
            bf8_t bf = *(const bf8_t*)&Bs[t * 16 + fm][quad * 8];
            acc[t] = __builtin_amdgcn_mfma_f32_16x16x32_bf16(af, bf, acc[t], 0, 0, 0);
        }
        __syncthreads();
    }
#pragma unroll
    for (int t = 0; t < 4; ++t) {
#pragma unroll
        for (int r = 0; r < 4; ++r) {
            int ml = wave * 16 + quad * 4 + r;
            int mr = m0 + ml;
            if (mr < segLen) {
                int n = n0 + t * 16 + fm;
                float v = acc[t][r];
                if (addBias) v += b2[(size_t)e * 512 + n];
                atomicAdd(&moe[(size_t)tokS[ml] * 512 + n], gateS[ml] * v);
            }
        }
    }
}

// ---------------------------------------------------------------------------
// LayerNorm(d=512) + affine + residual.
// ---------------------------------------------------------------------------
__device__ __forceinline__ float block_sum512(float v, float* red, int tid) {
#pragma unroll
    for (int off = 32; off > 0; off >>= 1) v += __shfl_xor(v, off);
    __syncthreads();
    if ((tid & 63) == 0) red[tid >> 6] = v;
    __syncthreads();
    return red[0] + red[1] + red[2] + red[3];
}

__global__ __launch_bounds__(256) void k_ln(const float* __restrict__ ot,
                                            const float* __restrict__ x,
                                            const float* __restrict__ g,
                                            const float* __restrict__ bb,
                                            float* __restrict__ out) {
    __shared__ float red[4];
    int t = blockIdx.x;
    int tid = threadIdx.x;
    const float* row = ot + (size_t)t * 512;
    float v0 = row[tid], v1 = row[tid + 256];
    float total = block_sum512(v0 + v1, red, tid);
    float mu = total * (1.f / 512.f);
    float q0 = v0 - mu, q1 = v1 - mu;
    float var = block_sum512(q0 * q0 + q1 * q1, red, tid) * (1.f / 512.f);
    float rstd = rsqrtf(var + 1e-5f);
    const float* xr = x + (size_t)t * 512;
    float* orow = out + (size_t)t * 512;
    orow[tid]       = q0 * rstd * g[tid]       + bb[tid]       + xr[tid];
    orow[tid + 256] = q1 * rstd * g[tid + 256] + bb[tid + 256] + xr[tid + 256];
}

// ---------------------------------------------------------------------------
// ws (floats): Y=[0:2*TOKD) = yf (padded) -> (moe f32 | hid bf16) -> ot.
// Phase 8 reuses the dead hid region [TOKD, 2*TOKD) as T1pair(2 slabs) +
// T2pair(2 slabs) — exactly 4*PB = TOKD floats.
// d_out: phase1 xt (dead after fft); then h + routing lists + Wr/br;
// phase8 otT; LN overwrites.
// ---------------------------------------------------------------------------
extern "C" void kernel_launch(void* const* d_in, const int* in_sizes, int n_in,
                              void* d_out, int out_size, void* d_ws, size_t ws_size,
                              hipStream_t stream) {
    const float* x        = (const float*)d_in[0];
    const float* pin_w    = (const float*)d_in[1];
    const float* pin_b    = (const float*)d_in[2];
    const float* router_w = (const float*)d_in[3];
    const float* router_b = (const float*)d_in[4];
    const float* w1       = (const float*)d_in[5];
    const float* b1       = (const float*)d_in[6];
    const float* w2       = (const float*)d_in[7];
    const float* b2       = (const float*)d_in[8];
    const float* pout_w   = (const float*)d_in[9];
    const float* pout_b   = (const float*)d_in[10];
    const float* ln_g     = (const float*)d_in[11];
    const float* ln_b     = (const float*)d_in[12];
    float* outf = (float*)d_out;

    float* Y   = (float*)d_ws;                    // yf; later moe|hid; later ot
    float* moe = Y;                               // (NTOK,512) f32
    unsigned short* hid_bf = (unsigned short*)(Y + C_TOKD);  // (NSLOT,512) bf16
    float* T1p = Y + C_TOKD;                      // 2 of_b slabs (hid dead)
    float* T2p = Y + C_TOKD + 2 * C_PB;           // 2 ofT_b slabs
    float* ot  = Y;                               // (B,S,D) final pre-LN

    float* xt    = outf;                          // (B,D,S)
    float* h     = outf;                          // (NTOK,512)
    float* topkw = outf + C_TOKD;
    float* gate  = topkw + C_NSLOT;
    int* topki   = (int*)(gate + C_NSLOT);
    int* tokl    = topki + C_NSLOT;
    int* counts  = tokl + C_NSLOT;                       // padded: 8*16 ints
    int* cursor  = counts + C_E * C_CSTRIDE;             // padded: 8*16 ints
    int* offsets = cursor + C_E * C_CSTRIDE;             // 9 ints
    float* wrbuf = outf + C_TOKD + (size_t)6 * C_NSLOT;  // (1024,8) fused Wr
    float* brbuf = wrbuf + 1024 * 8;                     // (8)
    float* otT   = outf;                          // (B,D,S)

    dim3 tb(32, 8);
    // 1. x (B,S,D) -> xt (B,D,S)
    k_transpose<<<dim3(C_D / 32, C_SEQ / 32, C_B), tb, 0, stream>>>(x, xt, C_SEQ, C_D);
    // 2. rfft (swizzled LDS + twiddle table); xt dead afterwards
    k_fft_fwd<<<C_B * C_D, 256, 0, stream>>>(xt, Y);
    // 3. fused router weights (f32 exact) + counter zero
    k_wr<<<32, 256, 0, stream>>>(pin_w, pin_b, router_w, router_b, wrbuf, brbuf);
    k_zero<<<4, 64, 0, stream>>>(counts, 2 * C_E * C_CSTRIDE);
    // 4. routing straight from yf (f32, split-K x4)
    k_router2<<<dim3(33, C_B), 256, 0, stream>>>(
        Y, wrbuf, brbuf, topki, topkw, counts);
    k_scan<<<1, 64, 0, stream>>>(counts, offsets, cursor);
    k_fill<<<(C_NTOK + 255) / 256, 256, 0, stream>>>(topki, topkw, cursor, tokl, gate);
    // 5. pin projection (bf16 MFMA) — h feeds experts only
    k_pin_mfma<<<dim3(33, 8, C_B), 256, 0, stream>>>(Y, pin_w, pin_b, h);
    // 6. moe zero AFTER pin (moe aliases yf region) — kernel, not memset
    k_zerof<<<2048, 256, 0, stream>>>(moe, (unsigned long long)C_TOKD);
    // 7. grouped expert MLP, bf16 MFMA (d_ff chunked by 512)
    for (int c = 0; c < C_NCHUNK; ++c) {
        int ffc0 = c * C_CHUNK;
        k_expert1<<<dim3(257, 8, C_E), 256, 0, stream>>>(
            h, w1, b1, offsets, tokl, hid_bf, ffc0);
        k_expert2<<<dim3(257, 8, C_E), 256, 0, stream>>>(
            hid_bf, w2, b2, offsets, tokl, gate, moe, ffc0, c == 0 ? 1 : 0);
    }
    // 8. per batch-PAIR: pout (z=2) -> T1p, transpose (z=2) -> T2p,
    //    irfft (1024 blocks) -> otT slabs. hid region reused as T1p/T2p.
    for (int b0 = 0; b0 < C_B; b0 += 2) {
        k_pout_mfma<<<dim3(33, 16, 2), 256, 0, stream>>>(moe, pout_w, pout_b, T1p, b0);
        k_transpose<<<dim3(1024 / 32, (C_FREQ + 31) / 32, 2), tb, 0, stream>>>(
            T1p, T2p, C_FREQ, 1024);
        k_fft_inv<<<1024, 256, 0, stream>>>(T2p, otT + (size_t)b0 * C_D * C_SEQ);
    }
    // 9. otT -> ot (B,S,D) in ws
    k_transpose<<<dim3(C_SEQ / 32, C_D / 32, C_B), tb, 0, stream>>>(otT, ot, C_D, C_SEQ);
    // 10. LN + residual
    k_ln<<<C_B * C_SEQ, 256, 0, stream>>>(ot, x, ln_g, ln_b, outf);
}

// Round 8
// 1468.146 us; speedup vs baseline: 1.5366x; 1.0700x over previous
//
#include <hip/hip_runtime.h>
#include <math.h>

#define PI_F 3.14159265358979323846f

// Problem sizes
#define C_SEQ   4096
#define C_B     8
#define C_D     512
#define C_FREQ  2049                  // SEQ/2+1
#define C_FPAD  2052                  // yf row stride (padded)
#define C_NTOK  (C_B * C_FREQ)        // 16392
#define C_NSLOT (2 * C_NTOK)          // 32784
#define C_CHUNK 512                   // d_ff chunk (hid is bf16)
#define C_NCHUNK 4
#define C_E     8
#define C_TOKD  ((size_t)C_NTOK * 512)   // 8,392,704 floats
#define C_PB    ((size_t)C_FREQ * 1024)  // 2,098,176 floats (one batch F-slab)
#define C_CSTRIDE 16                  // counter padding: 16 ints = 64B cacheline

typedef __attribute__((ext_vector_type(8))) short bf8_t;   // 8 bf16 (4 VGPRs)
typedef __attribute__((ext_vector_type(4))) float f4_t;    // MFMA acc

__device__ __forceinline__ unsigned short f2bf(float f) {
    union { float f; unsigned u; } v; v.f = f;
    unsigned r = v.u + 0x7FFF + ((v.u >> 16) & 1);   // RNE
    return (unsigned short)(r >> 16);
}

// ---------------------------------------------------------------------------
// Transpose: in (Z, R, C) -> out (Z, C, R); grid (ceil(C/32), ceil(R/32), Z)
// ---------------------------------------------------------------------------
__global__ __launch_bounds__(256) void k_transpose(const float* __restrict__ in,
                                                   float* __restrict__ out,
                                                   int R, int C) {
    __shared__ float t[32][33];
    int c0 = blockIdx.x * 32, r0 = blockIdx.y * 32;
    const float* inb = in + (size_t)blockIdx.z * R * C;
    float* outb = out + (size_t)blockIdx.z * R * C;
    int tx = threadIdx.x, ty = threadIdx.y;
#pragma unroll
    for (int i = 0; i < 4; ++i) {
        int r = r0 + ty + i * 8, c = c0 + tx;
        if (r < R && c < C) t[ty + i * 8][tx] = inb[(size_t)r * C + c];
    }
    __syncthreads();
#pragma unroll
    for (int i = 0; i < 4; ++i) {
        int c = c0 + ty + i * 8, r = r0 + tx;
        if (r < R && c < C) outb[(size_t)c * R + r] = t[tx][ty + i * 8];
    }
}

// ---------------------------------------------------------------------------
// 4096-pt in-place radix-2 DIT FFT in LDS (swizzled banks + twiddle table).
// REAL-PAIR packing: each block FFTs TWO real signals as one complex FFT
// (fwd) or two irffts as one complex inverse (inv) — halves FFT block count.
// ---------------------------------------------------------------------------
#define SW(i) ((i) ^ (((i) >> 6) & 31))

__device__ __forceinline__ int brev12(int x) {
    return (int)(__brev((unsigned)x) >> 20);
}

__device__ __forceinline__ void fft_twiddle_init(float* twr, float* twi, int tid) {
#pragma unroll
    for (int q = 0; q < 8; ++q) {
        int k = tid + q * 256;                      // 0..2047
        float sn, cs;
        __sincosf(-PI_F * (float)k / 2048.f, &sn, &cs);   // -2*pi*k/4096
        int a = SW(k);
        twr[a] = cs; twi[a] = sn;
    }
}

__device__ __forceinline__ void fft4096_inplace(float* re, float* im,
                                                const float* twr, const float* twi,
                                                int tid) {
    for (int s = 1; s <= 12; ++s) {
        int half = 1 << (s - 1);
        int shift = 12 - s;
        __syncthreads();
#pragma unroll
        for (int u = 0; u < 8; ++u) {
            int bf = tid + u * 256;                 // 0..2047
            int j = bf & (half - 1);
            int i1 = ((bf >> (s - 1)) << s) + j;
            int i2 = i1 + half;
            int a1 = SW(i1), a2 = SW(i2);
            int tw = SW(j << shift);
            float cs = twr[tw], sn = twi[tw];
            float ur = re[a1], ui = im[a1];
            float vr = re[a2], vi = im[a2];
            float tr = vr * cs - vi * sn;
            float ti = vr * sn + vi * cs;
            re[a1] = ur + tr; im[a1] = ui + ti;
            re[a2] = ur - tr; im[a2] = ui - ti;
        }
    }
    __syncthreads();
}

// rfft(ortho) PAIRED: xt (B, D, S) -> yf (B, 1024, FPAD).
// Block = (b, pair p): Z = FFT(x[d0] + i*x[d1]), d0=2p, d1=2p+1;
// unpack X1=(Z[k]+conj(Z[N-k]))/2, X2=(Z[k]-conj(Z[N-k]))/(2i).
// grid B*256 = 2048.
__global__ __launch_bounds__(256) void k_fft_fwd(const float* __restrict__ xt,
                                                 float* __restrict__ yf) {
    __shared__ float re[4096], im[4096], twr[2048], twi[2048];
    int tid = threadIdx.x;
    int b = blockIdx.x >> 8;
    int p = blockIdx.x & 255;
    int d0 = p * 2, d1 = d0 + 1;
    fft_twiddle_init(twr, twi, tid);
    const float* s0 = xt + ((size_t)b * C_D + d0) * C_SEQ;
    const float* s1 = s0 + C_SEQ;
    for (int i = tid; i < 4096; i += 256) {
        int r = SW(brev12(i));
        re[r] = s0[i];
        im[r] = s1[i];
    }
    fft4096_inplace(re, im, twr, twi, tid);
    float* o0r = yf + ((size_t)b * 1024 + d0) * C_FPAD;
    float* o0i = yf + ((size_t)b * 1024 + 512 + d0) * C_FPAD;
    float* o1r = yf + ((size_t)b * 1024 + d1) * C_FPAD;
    float* o1i = yf + ((size_t)b * 1024 + 512 + d1) * C_FPAD;
    const float hs = 0.5f / 64.f;                  // 0.5 * ortho scale
    for (int k = tid; k < C_FPAD; k += 256) {
        float x1r = 0.f, x1i = 0.f, x2r = 0.f, x2i = 0.f;
        if (k < C_FREQ) {
            int m = (4096 - k) & 4095;
            int ak = SW(k), am = SW(m);
            float zr = re[ak], zi = im[ak];
            float wr_ = re[am], wi_ = im[am];
            x1r = (zr + wr_) * hs;  x1i = (zi - wi_) * hs;
            x2r = (zi + wi_) * hs;  x2i = (wr_ - zr) * hs;
        }
        o0r[k] = x1r; o0i[k] = x1i;
        o1r[k] = x2r; o1i[k] = x2i;
    }
}

// irfft(ortho) PAIRED, TWO slabs per launch: ofTpair (2,1024,F) -> otT slabs.
// Block = (sub, pair p): Z[k] = X1[k] + i*X2[k] (conj-sym extension), one
// complex inverse FFT via conj(DFT(conj Z)); x1=Re, x2=-Im.
// grid 512: sub = blockIdx.x>>8, p = blockIdx.x&255.
__global__ __launch_bounds__(256) void k_fft_inv(const float* __restrict__ ofTpair,
                                                 float* __restrict__ otTpair) {
    __shared__ float re[4096], im[4096], twr[2048], twi[2048];
    int tid = threadIdx.x;
    int sub = blockIdx.x >> 8;
    int p = blockIdx.x & 255;
    int d0 = p * 2, d1 = d0 + 1;
    fft_twiddle_init(twr, twi, tid);
    const float* slab = ofTpair + (size_t)sub * C_PB;
    const float* x1r = slab + (size_t)d0 * C_FREQ;
    const float* x1i = slab + (size_t)(512 + d0) * C_FREQ;
    const float* x2r = slab + (size_t)d1 * C_FREQ;
    const float* x2i = slab + (size_t)(512 + d1) * C_FREQ;
    for (int i = tid; i < 4096; i += 256) {
        float zr, zi;
        if (i <= 2048) {
            zr = x1r[i] - x2i[i];
            zi = -(x1i[i] + x2r[i]);
        } else {
            int m = 4096 - i;
            zr = x1r[m] + x2i[m];
            zi = x1i[m] - x2r[m];
        }
        int r = SW(brev12(i));
        re[r] = zr;
        im[r] = zi;
    }
    fft4096_inplace(re, im, twr, twi, tid);
    float* dst0 = otTpair + (size_t)sub * C_D * C_SEQ + (size_t)d0 * C_SEQ;
    float* dst1 = otTpair + (size_t)sub * C_D * C_SEQ + (size_t)d1 * C_SEQ;
    const float scale = 1.f / 64.f;
    for (int n = tid; n < 4096; n += 256) {
        int a = SW(n);
        dst0[n] = re[a] * scale;
        dst1[n] = -im[a] * scale;
    }
}

// ---------------------------------------------------------------------------
// pin GEMM, bf16 MFMA: h[b,f,:] = yf[b]^T @ pin_w + pin_b.
// 64x64 tile, BK=32, 4 waves. grid (33, 8, B)
// ---------------------------------------------------------------------------
__global__ __launch_bounds__(256) void k_pin_mfma(const float* __restrict__ yf,
                                                  const float* __restrict__ pw,
                                                  const float* __restrict__ pb,
                                                  float* __restrict__ h) {
    int b = blockIdx.z;
    int m0 = blockIdx.x * 64;                      // f
    int n0 = blockIdx.y * 64;                      // out feature
    __shared__ unsigned short As[64][40];          // [m][k]
    __shared__ unsigned short Bs[64][40];          // [n][k]
    int tid = threadIdx.x;
    int wave = tid >> 6, lane = tid & 63;
    int fm = lane & 15, quad = lane >> 4;
    int sn = tid & 63, sk = (tid >> 6) * 8;        // staging: row, k-offset
    const float* Ab = yf + (size_t)b * 1024 * C_FPAD;
    bool mvalid = (m0 + sn) < C_FREQ;
    f4_t acc[4] = {{0,0,0,0},{0,0,0,0},{0,0,0,0},{0,0,0,0}};
    for (int k0 = 0; k0 < 1024; k0 += 32) {
        // A: strided-k coalesced-m reads (k-major source), pack -> [m][k]
        float av[8];
#pragma unroll
        for (int j = 0; j < 8; ++j)
            av[j] = mvalid ? Ab[(size_t)(k0 + sk + j) * C_FPAD + m0 + sn] : 0.f;
        uint4 pa;
        pa.x = f2bf(av[0]) | ((unsigned)f2bf(av[1]) << 16);
        pa.y = f2bf(av[2]) | ((unsigned)f2bf(av[3]) << 16);
        pa.z = f2bf(av[4]) | ((unsigned)f2bf(av[5]) << 16);
        pa.w = f2bf(av[6]) | ((unsigned)f2bf(av[7]) << 16);
        *(uint4*)&As[sn][sk] = pa;
        // B: same pattern, stride 512
        float bv[8];
#pragma unroll
        for (int j = 0; j < 8; ++j)
            bv[j] = pw[(size_t)(k0 + sk + j) * 512 + n0 + sn];
        uint4 pbk;
        pbk.x = f2bf(bv[0]) | ((unsigned)f2bf(bv[1]) << 16);
        pbk.y = f2bf(bv[2]) | ((unsigned)f2bf(bv[3]) << 16);
        pbk.z = f2bf(bv[4]) | ((unsigned)f2bf(bv[5]) << 16);
        pbk.w = f2bf(bv[6]) | ((unsigned)f2bf(bv[7]) << 16);
        *(uint4*)&Bs[sn][sk] = pbk;
        __syncthreads();
        bf8_t af = *(const bf8_t*)&As[wave * 16 + fm][quad * 8];
#pragma unroll
        for (int t = 0; t < 4; ++t) {
            bf8_t bf = *(const bf8_t*)&Bs[t * 16 + fm][quad * 8];
            acc[t] = __builtin_amdgcn_mfma_f32_16x16x32_bf16(af, bf, acc[t], 0, 0, 0);
        }
        __syncthreads();
    }
    // epilogue: C/D layout col=lane&15, row=quad*4+reg
#pragma unroll
    for (int t = 0; t < 4; ++t) {
#pragma unroll
        for (int r = 0; r < 4; ++r) {
            int m = m0 + wave * 16 + quad * 4 + r;
            if (m < C_FREQ) {
                int n = n0 + t * 16 + fm;
                h[((size_t)b * C_FREQ + m) * 512 + n] = acc[t][r] + pb[n];
            }
        }
    }
}

// ---------------------------------------------------------------------------
// pout GEMM, bf16 MFMA, TWO batches per launch: of = moe_b @ pout_w + pout_b
// (F,512)x(512,1024). grid (33, 16, 2); z selects batch b0+z, slab z*PB.
// ---------------------------------------------------------------------------
__global__ __launch_bounds__(256) void k_pout_mfma(const float* __restrict__ moe,
                                                   const float* __restrict__ pw,
                                                   const float* __restrict__ pb,
                                                   float* __restrict__ ofpair,
                                                   int b0) {
    int z = blockIdx.z;
    const float* moeb = moe + (size_t)(b0 + z) * C_FREQ * 512;
    float* ofb = ofpair + (size_t)z * C_PB;
    int m0 = blockIdx.x * 64;                      // f
    int n0 = blockIdx.y * 64;                      // out col of 1024
    __shared__ unsigned short As[64][40];
    __shared__ unsigned short Bs[64][40];
    int tid = threadIdx.x;
    int wave = tid >> 6, lane = tid & 63;
    int fm = lane & 15, quad = lane >> 4;
    int ar = tid >> 2, ak = (tid & 3) * 8;         // A: row, k-off
    int bn = tid & 63, bk = (tid >> 6) * 8;        // B: n, k-off
    bool avalid = (m0 + ar) < C_FREQ;
    f4_t acc[4] = {{0,0,0,0},{0,0,0,0},{0,0,0,0},{0,0,0,0}};
    for (int k0 = 0; k0 < 512; k0 += 32) {
        // A: row-major f32 -> bf16 [m][k]
        float4 a0 = make_float4(0,0,0,0), a1 = make_float4(0,0,0,0);
        if (avalid) {
            const float4* ap = (const float4*)&moeb[(size_t)(m0 + ar) * 512 + k0 + ak];
            a0 = ap[0]; a1 = ap[1];
        }
        uint4 pa;
        pa.x = f2bf(a0.x) | ((unsigned)f2bf(a0.y) << 16);
        pa.y = f2bf(a0.z) | ((unsigned)f2bf(a0.w) << 16);
        pa.z = f2bf(a1.x) | ((unsigned)f2bf(a1.y) << 16);
        pa.w = f2bf(a1.z) | ((unsigned)f2bf(a1.w) << 16);
        *(uint4*)&As[ar][ak] = pa;
        // B: strided-k coalesced-n (stride 1024), pack -> [n][k]
        float bv[8];
#pragma unroll
        for (int j = 0; j < 8; ++j)
            bv[j] = pw[(size_t)(k0 + bk + j) * 1024 + n0 + bn];
        uint4 pbk;
        pbk.x = f2bf(bv[0]) | ((unsigned)f2bf(bv[1]) << 16);
        pbk.y = f2bf(bv[2]) | ((unsigned)f2bf(bv[3]) << 16);
        pbk.z = f2bf(bv[4]) | ((unsigned)f2bf(bv[5]) << 16);
        pbk.w = f2bf(bv[6]) | ((unsigned)f2bf(bv[7]) << 16);
        *(uint4*)&Bs[bn][bk] = pbk;
        __syncthreads();
        bf8_t af = *(const bf8_t*)&As[wave * 16 + fm][quad * 8];
#pragma unroll
        for (int t = 0; t < 4; ++t) {
            bf8_t bf = *(const bf8_t*)&Bs[t * 16 + fm][quad * 8];
            acc[t] = __builtin_amdgcn_mfma_f32_16x16x32_bf16(af, bf, acc[t], 0, 0, 0);
        }
        __syncthreads();
    }
#pragma unroll
    for (int t = 0; t < 4; ++t) {
#pragma unroll
        for (int r = 0; r < 4; ++r) {
            int m = m0 + wave * 16 + quad * 4 + r;
            if (m < C_FREQ) {
                int n = n0 + t * 16 + fm;
                ofb[(size_t)m * 1024 + n] = acc[t][r] + pb[n];
            }
        }
    }
}

__global__ void k_zero(int* p, int n) {
    int i = blockIdx.x * 64 + threadIdx.x;
    if (i < n) p[i] = 0;
}

// grid-stride f32 zero (NOT hipMemsetAsync — graph-capture safe)
__global__ __launch_bounds__(256) void k_zerof(float* __restrict__ p, unsigned long long n) {
    unsigned long long i = (unsigned long long)blockIdx.x * 256 + threadIdx.x;
    unsigned long long stride = (unsigned long long)gridDim.x * 256;
    for (; i < n; i += stride) p[i] = 0.f;
}

// ---------------------------------------------------------------------------
// Fused router weights (f32, exact): Wr = pin_w @ router_w  (1024 x 8),
// br = pin_b @ router_w + router_b. grid (32) x 256: thread=(k,e).
// ---------------------------------------------------------------------------
__global__ __launch_bounds__(256) void k_wr(const float* __restrict__ pin_w,
                                            const float* __restrict__ pin_b,
                                            const float* __restrict__ rw,
                                            const float* __restrict__ rb,
                                            float* __restrict__ wr,
                                            float* __restrict__ brv) {
    int k = blockIdx.x * 32 + (threadIdx.x >> 3);
    int e = threadIdx.x & 7;
    const float* pr = &pin_w[(size_t)k * 512];
    float s = 0.f;
    for (int d = 0; d < 512; ++d) s += pr[d] * rw[d * 8 + e];
    wr[k * 8 + e] = s;
    if (blockIdx.x == 0 && threadIdx.x < 8) {
        float s2 = 0.f;
        for (int d = 0; d < 512; ++d) s2 += pin_b[d] * rw[d * 8 + e];
        brv[e] = s2 + rb[e];
    }
}

// ---------------------------------------------------------------------------
// Router v5: split-K x4 for occupancy. Block = 64 tokens x 4 k-quarters;
// LDS partials (+1 pad), 1 wave finishes. grid (33, B).
// ---------------------------------------------------------------------------
__global__ __launch_bounds__(256) void k_router2(const float* __restrict__ yf,
                                                 const float* __restrict__ wr,
                                                 const float* __restrict__ brv,
                                                 int* __restrict__ topk_idx,
                                                 float* __restrict__ topk_w,
                                                 int* __restrict__ counts) {
    __shared__ float part[4][64][9];               // +1 pad: stride 9 coprime 32
    __shared__ int lc[C_E];
    int tid = threadIdx.x;
    int lane = tid & 63, kq = tid >> 6;
    if (tid < C_E) lc[tid] = 0;
    int b = blockIdx.y;
    int f = blockIdx.x * 64 + lane;
    bool valid = (f < C_FREQ);
    int fc = valid ? f : (C_FREQ - 1);
    const float* Ab = yf + (size_t)b * 1024 * C_FPAD + fc;
    float lg[8] = {};
    int kbeg = kq * 256;
#pragma unroll 4
    for (int k = kbeg; k < kbeg + 256; ++k) {
        float a = Ab[(size_t)k * C_FPAD];          // coalesced across lanes
        const float* w = &wr[k * 8];               // wave-uniform -> s_load
#pragma unroll
        for (int e = 0; e < 8; ++e) lg[e] += a * w[e];
    }
#pragma unroll
    for (int e = 0; e < 8; ++e) part[kq][lane][e] = lg[e];
    __syncthreads();
    if (tid < 64 && (blockIdx.x * 64 + tid) < C_FREQ) {
        int ff = blockIdx.x * 64 + tid;
        float v[8];
#pragma unroll
        for (int e = 0; e < 8; ++e)
            v[e] = part[0][tid][e] + part[1][tid][e] + part[2][tid][e]
                 + part[3][tid][e] + brv[e];
        int i1 = 0;
        for (int q = 1; q < 8; ++q) if (v[q] > v[i1]) i1 = q;
        int i2 = -1;
        for (int q = 0; q < 8; ++q)
            if (q != i1 && (i2 < 0 || v[q] > v[i2])) i2 = q;
        float w1 = 1.f / (1.f + __expf(v[i2] - v[i1]));
        int t = b * C_FREQ + ff;
        topk_idx[t * 2] = i1; topk_idx[t * 2 + 1] = i2;
        topk_w[t * 2] = w1;   topk_w[t * 2 + 1] = 1.f - w1;
        atomicAdd(&lc[i1], 1);
        atomicAdd(&lc[i2], 1);
    }
    __syncthreads();
    if (tid < C_E) {
        int c = lc[tid];
        if (c > 0) atomicAdd(&counts[tid * C_CSTRIDE], c);
    }
}

__global__ void k_scan(const int* __restrict__ counts, int* __restrict__ offsets,
                       int* __restrict__ cursor) {
    if (threadIdx.x == 0) {
        int acc = 0;
        for (int e = 0; e < C_E; ++e) {
            offsets[e] = acc;
            cursor[e * C_CSTRIDE] = acc;
            acc += counts[e * C_CSTRIDE];
        }
        offsets[C_E] = acc;
    }
}

// ---------------------------------------------------------------------------
// Fill: block-level two-phase reservation (LDS histogram + rank, one
// padded global atomic per expert per block, conflict-free scatter).
// ---------------------------------------------------------------------------
__global__ __launch_bounds__(256) void k_fill(const int* __restrict__ topk_idx,
                                              const float* __restrict__ topk_w,
                                              int* __restrict__ cursor,
                                              int* __restrict__ tok_list,
                                              float* __restrict__ gate_list) {
    __shared__ int lc[C_E];
    __shared__ int lbase[C_E];
    int tid = threadIdx.x;
    if (tid < C_E) lc[tid] = 0;
    __syncthreads();
    int t = blockIdx.x * 256 + tid;
    int e0 = 0, e1 = 0, p0 = 0, p1 = 0;
    float w0 = 0.f, w1 = 0.f;
    bool valid = (t < C_NTOK);
    if (valid) {
        e0 = topk_idx[t * 2];     e1 = topk_idx[t * 2 + 1];
        w0 = topk_w[t * 2];       w1 = topk_w[t * 2 + 1];
        p0 = atomicAdd(&lc[e0], 1);
        p1 = atomicAdd(&lc[e1], 1);
    }
    __syncthreads();
    if (tid < C_E) {
        int c = lc[tid];
        lbase[tid] = (c > 0) ? atomicAdd(&cursor[tid * C_CSTRIDE], c) : 0;
    }
    __syncthreads();
    if (valid) {
        int pos0 = lbase[e0] + p0;
        tok_list[pos0] = t; gate_list[pos0] = w0;
        int pos1 = lbase[e1] + p1;
        tok_list[pos1] = t; gate_list[pos1] = w1;
    }
}

// ---------------------------------------------------------------------------
// Expert layer 1 (bf16 MFMA): hid_bf[slot] = gelu(h[tok] @ w1[e][:,ffc0:+512])
// Tile 64x64, BK=32, 4 waves. grid (257, 8, E)
// ---------------------------------------------------------------------------
__global__ __launch_bounds__(256) void k_expert1(const float* __restrict__ h,
                                                 const float* __restrict__ w1,
                                                 const float* __restrict__ b1,
                                                 const int* __restrict__ offsets,
                                                 const int* __restrict__ tok_list,
                                                 unsigned short* __restrict__ hid_bf,
                                                 int ffc0) {
    int e = blockIdx.z;
    int segStart = offsets[e], segEnd = offsets[e + 1];
    int segLen = segEnd - segStart;
    int m0 = blockIdx.x * 64;
    if (m0 >= segLen) return;
    int n0 = blockIdx.y * 64;                      // within chunk [0,512)
    __shared__ unsigned short As[64][40];          // [m][k] pad->80B rows
    __shared__ unsigned short Bs[64][40];          // [n][k]
    __shared__ int tok[64];
    int tid = threadIdx.x;
    if (tid < 64) {
        int mr = m0 + tid;
        tok[tid] = (mr < segLen) ? tok_list[segStart + mr] : -1;
    }
    __syncthreads();
    int wave = tid >> 6, lane = tid & 63;
    int fm = lane & 15, quad = lane >> 4;
    int ar = tid >> 2, ak = (tid & 3) * 8;         // A staging: row, k-off
    int bn = tid & 63, bk = (tid >> 6) * 8;        // B staging: n, k-off
    const float* w1e = w1 + (size_t)e * 512 * 2048 + ffc0;
    f4_t acc[4] = {{0,0,0,0},{0,0,0,0},{0,0,0,0},{0,0,0,0}};
    for (int k0 = 0; k0 < 512; k0 += 32) {
        // A: gather + convert
        float4 a0 = make_float4(0,0,0,0), a1 = make_float4(0,0,0,0);
        int trow = tok[ar];
        if (trow >= 0) {
            const float4* hp = (const float4*)&h[(size_t)trow * 512 + k0 + ak];
            a0 = hp[0]; a1 = hp[1];
        }
        uint4 pa;
        pa.x = f2bf(a0.x) | ((unsigned)f2bf(a0.y) << 16);
        pa.y = f2bf(a0.z) | ((unsigned)f2bf(a0.w) << 16);
        pa.z = f2bf(a1.x) | ((unsigned)f2bf(a1.y) << 16);
        pa.w = f2bf(a1.z) | ((unsigned)f2bf(a1.w) << 16);
        *(uint4*)&As[ar][ak] = pa;
        // B: strided-k coalesced-n reads + convert (transpose into [n][k])
        float bv[8];
#pragma unroll
        for (int j = 0; j < 8; ++j)
            bv[j] = w1e[(size_t)(k0 + bk + j) * 2048 + n0 + bn];
        uint4 pbk;
        pbk.x = f2bf(bv[0]) | ((unsigned)f2bf(bv[1]) << 16);
        pbk.y = f2bf(bv[2]) | ((unsigned)f2bf(bv[3]) << 16);
        pbk.z = f2bf(bv[4]) | ((unsigned)f2bf(bv[5]) << 16);
        pbk.w = f2bf(bv[6]) | ((unsigned)f2bf(bv[7]) << 16);
        *(uint4*)&Bs[bn][bk] = pbk;
        __syncthreads();
        bf8_t af = *(const bf8_t*)&As[wave * 16 + fm][quad * 8];
#pragma unroll
        for (int t = 0; t < 4; ++t) {
            bf8_t bf = *(const bf8_t*)&Bs[t * 16 + fm][quad * 8];
            acc[t] = __builtin_amdgcn_mfma_f32_16x16x32_bf16(af, bf, acc[t], 0, 0, 0);
        }
        __syncthreads();
    }
    // epilogue: C/D layout col=lane&15, row=quad*4+reg
#pragma unroll
    for (int t = 0; t < 4; ++t) {
#pragma unroll
        for (int r = 0; r < 4; ++r) {
            int ml = wave * 16 + quad * 4 + r;
            int mr = m0 + ml;
            if (mr < segLen) {
                int n = n0 + t * 16 + fm;
                float xv = acc[t][r] + b1[(size_t)e * 2048 + ffc0 + n];
                float gl = 0.5f * xv * (1.f + erff(xv * 0.70710678118654752f));
                hid_bf[(size_t)(segStart + mr) * C_CHUNK + n] = f2bf(gl);
            }
        }
    }
}

// ---------------------------------------------------------------------------
// Expert layer 2 (bf16 MFMA): moe[tok] += gate*(hid_bf @ w2[e][ffc0:+512,:])
// K=512(chunk), N=512. grid (257, 8, E)
// ---------------------------------------------------------------------------
__global__ __launch_bounds__(256) void k_expert2(const unsigned short* __restrict__ hid_bf,
                                                 const float* __restrict__ w2,
                                                 const float* __restrict__ b2,
                                                 const int* __restrict__ offsets,
                                                 const int* __restrict__ tok_list,
                                                 const float* __restrict__ gate_list,
                                                 float* __restrict__ moe,
                                                 int ffc0, int addBias) {
    int e = blockIdx.z;
    int segStart = offsets[e], segEnd = offsets[e + 1];
    int segLen = segEnd - segStart;
    int m0 = blockIdx.x * 64;
    if (m0 >= segLen) return;
    int n0 = blockIdx.y * 64;                      // within d_model [0,512)
    __shared__ unsigned short As[64][40];
    __shared__ unsigned short Bs[64][40];
    __shared__ int tokS[64];
    __shared__ float gateS[64];
    int tid = threadIdx.x;
    if (tid < 64) {
        int mr = m0 + tid;
        tokS[tid]  = (mr < segLen) ? tok_list[segStart + mr] : 0;
        gateS[tid] = (mr < segLen) ? gate_list[segStart + mr] : 0.f;
    }
    __syncthreads();
    int wave = tid >> 6, lane = tid & 63;
    int fm = lane & 15, quad = lane >> 4;
    int ar = tid >> 2, ak = (tid & 3) * 8;
    int bn = tid & 63, bk = (tid >> 6) * 8;
    const float* w2e = w2 + (size_t)e * 2048 * 512 + (size_t)ffc0 * 512;
    f4_t acc[4] = {{0,0,0,0},{0,0,0,0},{0,0,0,0},{0,0,0,0}};
    for (int k0 = 0; k0 < C_CHUNK; k0 += 32) {
        // A: hid_bf rows are contiguous slots (no gather), already bf16
        uint4 pa = make_uint4(0, 0, 0, 0);
        if (m0 + ar < segLen)
            pa = *(const uint4*)&hid_bf[(size_t)(segStart + m0 + ar) * C_CHUNK + k0 + ak];
        *(uint4*)&As[ar][ak] = pa;
        // B: w2 f32 -> bf16, transpose into [n][k]
        float bv[8];
#pragma unroll
        for (int j = 0; j < 8; ++j)
            bv[j] = w2e[(size_t)(k0 + bk + j) * 512 + n0 + bn];
        uint4 pbk;
        pbk.x = f2bf(bv[0]) | ((unsigned)f2bf(bv[1]) << 16);
        pbk.y = f2bf(bv[2]) | ((unsigned)f2bf(bv[3]) << 16);
        pbk.z = f2bf(bv[4]) | ((unsigned)f2bf(bv[5]) << 16);
        pbk.w = f2bf(bv[6]) | ((unsigned)f2bf(bv[7]) << 16);
        *(uint4*)&Bs[bn][bk] = pbk;
        __syncthreads();
        bf8_t af = *(const bf8_t*)&As[wave * 16 + fm][quad * 8];
#pragma unroll
        for (int t = 0; t < 4; ++t) {
            bf8_t bf = *(const bf8_t*)&Bs[t * 16 + fm][quad * 8];
            acc[t] = __builtin_amdgcn_mfma_f32_16x16x32_bf16(af, bf, acc[t], 0, 0, 0);
        }
        __syncthreads();
    }
#pragma unroll
    for (int t = 0; t < 4; ++t) {
#pragma unroll
        for (int r = 0; r < 4; ++r) {
            int ml = wave * 16 + quad * 4 + r;
            int mr = m0 + ml;
            if (mr < segLen) {
                int n = n0 + t * 16 + fm;
                float v = acc[t][r];
                if (addBias) v += b2[(size_t)e * 512 + n];
                atomicAdd(&moe[(size_t)tokS[ml] * 512 + n], gateS[ml] * v);
            }
        }
    }
}

// ---------------------------------------------------------------------------
// LayerNorm(d=512) + affine + residual.
// ---------------------------------------------------------------------------
__device__ __forceinline__ float block_sum512(float v, float* red, int tid) {
#pragma unroll
    for (int off = 32; off > 0; off >>= 1) v += __shfl_xor(v, off);
    __syncthreads();
    if ((tid & 63) == 0) red[tid >> 6] = v;
    __syncthreads();
    return red[0] + red[1] + red[2] + red[3];
}

__global__ __launch_bounds__(256) void k_ln(const float* __restrict__ ot,
                                            const float* __restrict__ x,
                                            const float* __restrict__ g,
                                            const float* __restrict__ bb,
                                            float* __restrict__ out) {
    __shared__ float red[4];
    int t = blockIdx.x;
    int tid = threadIdx.x;
    const float* row = ot + (size_t)t * 512;
    float v0 = row[tid], v1 = row[tid + 256];
    float total = block_sum512(v0 + v1, red, tid);
    float mu = total * (1.f / 512.f);
    float q0 = v0 - mu, q1 = v1 - mu;
    float var = block_sum512(q0 * q0 + q1 * q1, red, tid) * (1.f / 512.f);
    float rstd = rsqrtf(var + 1e-5f);
    const float* xr = x + (size_t)t * 512;
    float* orow = out + (size_t)t * 512;
    orow[tid]       = q0 * rstd * g[tid]       + bb[tid]       + xr[tid];
    orow[tid + 256] = q1 * rstd * g[tid + 256] + bb[tid + 256] + xr[tid + 256];
}

// ---------------------------------------------------------------------------
// ws (floats): Y=[0:2*TOKD) = yf (padded) -> (moe f32 | hid bf16) -> ot.
// Phase 8 reuses the dead hid region [TOKD, 2*TOKD) as T1pair(2 slabs) +
// T2pair(2 slabs) — exactly 4*PB = TOKD floats.
// d_out: phase1 xt (dead after fft); then h + routing lists + Wr/br;
// phase8 otT; LN overwrites.
// ---------------------------------------------------------------------------
extern "C" void kernel_launch(void* const* d_in, const int* in_sizes, int n_in,
                              void* d_out, int out_size, void* d_ws, size_t ws_size,
                              hipStream_t stream) {
    const float* x        = (const float*)d_in[0];
    const float* pin_w    = (const float*)d_in[1];
    const float* pin_b    = (const float*)d_in[2];
    const float* router_w = (const float*)d_in[3];
    const float* router_b = (const float*)d_in[4];
    const float* w1       = (const float*)d_in[5];
    const float* b1       = (const float*)d_in[6];
    const float* w2       = (const float*)d_in[7];
    const float* b2       = (const float*)d_in[8];
    const float* pout_w   = (const float*)d_in[9];
    const float* pout_b   = (const float*)d_in[10];
    const float* ln_g     = (const float*)d_in[11];
    const float* ln_b     = (const float*)d_in[12];
    float* outf = (float*)d_out;

    float* Y   = (float*)d_ws;                    // yf; later moe|hid; later ot
    float* moe = Y;                               // (NTOK,512) f32
    unsigned short* hid_bf = (unsigned short*)(Y + C_TOKD);  // (NSLOT,512) bf16
    float* T1p = Y + C_TOKD;                      // 2 of_b slabs (hid dead)
    float* T2p = Y + C_TOKD + 2 * C_PB;           // 2 ofT_b slabs
    float* ot  = Y;                               // (B,S,D) final pre-LN

    float* xt    = outf;                          // (B,D,S)
    float* h     = outf;                          // (NTOK,512)
    float* topkw = outf + C_TOKD;
    float* gate  = topkw + C_NSLOT;
    int* topki   = (int*)(gate + C_NSLOT);
    int* tokl    = topki + C_NSLOT;
    int* counts  = tokl + C_NSLOT;                       // padded: 8*16 ints
    int* cursor  = counts + C_E * C_CSTRIDE;             // padded: 8*16 ints
    int* offsets = cursor + C_E * C_CSTRIDE;             // 9 ints
    float* wrbuf = outf + C_TOKD + (size_t)6 * C_NSLOT;  // (1024,8) fused Wr
    float* brbuf = wrbuf + 1024 * 8;                     // (8)
    float* otT   = outf;                          // (B,D,S)

    dim3 tb(32, 8);
    // 1. x (B,S,D) -> xt (B,D,S)
    k_transpose<<<dim3(C_D / 32, C_SEQ / 32, C_B), tb, 0, stream>>>(x, xt, C_SEQ, C_D);
    // 2. rfft PAIRED (2 signals per block); xt dead afterwards
    k_fft_fwd<<<C_B * 256, 256, 0, stream>>>(xt, Y);
    // 3. fused router weights (f32 exact) + counter zero
    k_wr<<<32, 256, 0, stream>>>(pin_w, pin_b, router_w, router_b, wrbuf, brbuf);
    k_zero<<<4, 64, 0, stream>>>(counts, 2 * C_E * C_CSTRIDE);
    // 4. routing straight from yf (f32, split-K x4)
    k_router2<<<dim3(33, C_B), 256, 0, stream>>>(
        Y, wrbuf, brbuf, topki, topkw, counts);
    k_scan<<<1, 64, 0, stream>>>(counts, offsets, cursor);
    k_fill<<<(C_NTOK + 255) / 256, 256, 0, stream>>>(topki, topkw, cursor, tokl, gate);
    // 5. pin projection (bf16 MFMA) — h feeds experts only
    k_pin_mfma<<<dim3(33, 8, C_B), 256, 0, stream>>>(Y, pin_w, pin_b, h);
    // 6. moe zero AFTER pin (moe aliases yf region) — kernel, not memset
    k_zerof<<<2048, 256, 0, stream>>>(moe, (unsigned long long)C_TOKD);
    // 7. grouped expert MLP, bf16 MFMA (d_ff chunked by 512)
    for (int c = 0; c < C_NCHUNK; ++c) {
        int ffc0 = c * C_CHUNK;
        k_expert1<<<dim3(257, 8, C_E), 256, 0, stream>>>(
            h, w1, b1, offsets, tokl, hid_bf, ffc0);
        k_expert2<<<dim3(257, 8, C_E), 256, 0, stream>>>(
            hid_bf, w2, b2, offsets, tokl, gate, moe, ffc0, c == 0 ? 1 : 0);
    }
    // 8. per batch-PAIR: pout (z=2) -> T1p, transpose (z=2) -> T2p,
    //    irfft PAIRED (512 blocks) -> otT slabs.
    for (int b0 = 0; b0 < C_B; b0 += 2) {
        k_pout_mfma<<<dim3(33, 16, 2), 256, 0, stream>>>(moe, pout_w, pout_b, T1p, b0);
        k_transpose<<<dim3(1024 / 32, (C_FREQ + 31) / 32, 2), tb, 0, stream>>>(
            T1p, T2p, C_FREQ, 1024);
        k_fft_inv<<<512, 256, 0, stream>>>(T2p, otT + (size_t)b0 * C_D * C_SEQ);
    }
    // 9. otT -> ot (B,S,D) in ws
    k_transpose<<<dim3(C_SEQ / 32, C_D / 32, C_B), tb, 0, stream>>>(otT, ot, C_D, C_SEQ);
    // 10. LN + residual
    k_ln<<<C_B * C_SEQ, 256, 0, stream>>>(ot, x, ln_g, ln_b, outf);
}